// Round 1
// baseline (9699.975 us; speedup 1.0000x reference)
//
#include <hip/hip_runtime.h>
#include <math.h>

#define HD 128

__device__ __forceinline__ void atomicMaxFloat(float* addr, float val) {
  if (val >= 0.f) atomicMax((int*)addr, __float_as_int(val));
  else atomicMin((unsigned int*)addr, __float_as_uint(val));
}

__global__ void init_kernel(float* gmax, float* gsum, float* pooled, float* stats, int G) {
  int idx = blockIdx.x * blockDim.x + threadIdx.x;
  if (idx < G) { gmax[idx] = -INFINITY; gsum[idx] = 0.f; }
  if (idx < G * HD) pooled[idx] = 0.f;
  if (idx < 7 * 256) stats[idx] = 0.f;
}

__global__ void encode_kernel(const int* __restrict__ x, const float* __restrict__ pe,
                              const float* __restrict__ ce, const float* __restrict__ le,
                              float* __restrict__ h, int n) {
  int total = n * HD;
  int stride = gridDim.x * blockDim.x;
  for (int idx = blockIdx.x * blockDim.x + threadIdx.x; idx < total; idx += stride) {
    int node = idx >> 7, c = idx & (HD - 1);
    int lv = x[node * 3 + 0]; lv = lv < 0 ? 0 : (lv > 999 ? 999 : lv);
    int ct = x[node * 3 + 1]; ct = ct < 0 ? 0 : (ct > 4 ? 4 : ct);
    int th = x[node * 3 + 2]; th = th < 0 ? 0 : (th > 4999 ? 4999 : th);
    h[idx] = ce[ct * HD + c] + le[lv * HD + c] + pe[th * HD + c];
  }
}

// agg[dst] += h[src], one 32-lane group per edge, float4 per lane
__global__ void scatter_kernel(const float* __restrict__ h, const int* __restrict__ ei,
                               float* agg, int E) {
  int gid = (blockIdx.x * blockDim.x + threadIdx.x) >> 5;
  int lane = threadIdx.x & 31;
  int ng = (gridDim.x * blockDim.x) >> 5;
  for (int e = gid; e < E; e += ng) {
    int s = ei[e];
    int d = ei[E + e];
    float4 v = *(const float4*)(h + (size_t)s * HD + lane * 4);
    float* p = agg + (size_t)d * HD + lane * 4;
    atomicAdd(p + 0, v.x);
    atomicAdd(p + 1, v.y);
    atomicAdd(p + 2, v.z);
    atomicAdd(p + 3, v.w);
  }
}

// out[16 rows] = op(X [+X2] [bn+relu]) @ W + bias ; W [128,128] row-major (k, c)
// thread t: row r = t>>4, columns c = (t&15) + 16*j, j=0..7  (conflict-free LDS)
template<bool ADD, bool INBN, bool OUTRELU>
__global__ __launch_bounds__(256)
void gemm128_kernel(const float* X, const float* __restrict__ X2,
                    const float* __restrict__ W, const float* __restrict__ bias,
                    const float* __restrict__ ab, float* out) {
  __shared__ float Ws[64 * HD];
  __shared__ float Xs[16][132];
  int t = threadIdx.x;
  size_t base = (size_t)blockIdx.x * 16 * HD;

  for (int i = t * 4; i < 16 * HD; i += 1024) {
    float4 v = *(const float4*)(X + base + i);
    if (ADD) {
      float4 u = *(const float4*)(X2 + base + i);
      v.x += u.x; v.y += u.y; v.z += u.z; v.w += u.w;
    }
    int cc = i & (HD - 1);
    if (INBN) {
      float4 a = *(const float4*)(ab + cc);
      float4 b = *(const float4*)(ab + HD + cc);
      v.x = fmaxf(v.x * a.x + b.x, 0.f);
      v.y = fmaxf(v.y * a.y + b.y, 0.f);
      v.z = fmaxf(v.z * a.z + b.z, 0.f);
      v.w = fmaxf(v.w * a.w + b.w, 0.f);
    }
    *(float4*)&Xs[i >> 7][cc] = v;
  }

  int cg = t & 15, r = t >> 4;
  float acc[8];
#pragma unroll
  for (int j = 0; j < 8; j++) acc[j] = bias[cg + j * 16];

  for (int half = 0; half < 2; half++) {
    __syncthreads();   // Xs ready (half 0) / Ws reuse safe (half 1)
    for (int i = t * 4; i < 64 * HD; i += 1024)
      *(float4*)&Ws[i] = *(const float4*)(W + half * 64 * HD + i);
    __syncthreads();
    int kb = half * 64;
    for (int k = 0; k < 64; k++) {
      float a = Xs[r][kb + k];
#pragma unroll
      for (int j = 0; j < 8; j++) acc[j] += a * Ws[k * HD + cg + j * 16];
    }
  }

  float* o = out + base + (size_t)r * HD;
#pragma unroll
  for (int j = 0; j < 8; j++) {
    float v = acc[j];
    if (OUTRELU) v = fmaxf(v, 0.f);
    o[cg + j * 16] = v;
  }
}

// column sums / sumsq for BatchNorm
__global__ void stats_kernel(const float* __restrict__ z, float* stat, int n) {
  int c = threadIdx.x & (HD - 1);
  int rg = threadIdx.x >> 7;
  float s = 0.f, ss = 0.f;
  for (int r = blockIdx.x * 2 + rg; r < n; r += gridDim.x * 2) {
    float v = z[(size_t)r * HD + c];
    s += v; ss += v * v;
  }
  __shared__ float S[2][HD], SS[2][HD];
  S[rg][c] = s; SS[rg][c] = ss;
  __syncthreads();
  if (threadIdx.x < HD) {
    atomicAdd(&stat[c], S[0][c] + S[1][c]);
    atomicAdd(&stat[HD + c], SS[0][c] + SS[1][c]);
  }
}

__global__ void finalize_kernel(const float* __restrict__ stat, const float* __restrict__ g,
                                const float* __restrict__ be, float* ab, float inv_n) {
  int c = threadIdx.x;
  float mean = stat[c] * inv_n;
  float var = stat[HD + c] * inv_n - mean * mean;
  float inv = rsqrtf(var + 1e-5f);
  float a = inv * g[c];
  ab[c] = a;
  ab[HD + c] = be[c] - mean * a;
}

__global__ void bnrelu_kernel(float* z, const float* __restrict__ ab, int total) {
  int stride = gridDim.x * blockDim.x;
  for (int idx = blockIdx.x * blockDim.x + threadIdx.x; idx < total; idx += stride) {
    int c = idx & (HD - 1);
    z[idx] = fmaxf(z[idx] * ab[c] + ab[HD + c], 0.f);
  }
}

// gate[i] = dot(u[i], w2) + b2 ; also per-graph atomic max
__global__ void gate_kernel(const float* __restrict__ u, const float* __restrict__ w2,
                            const float* __restrict__ b2, const int* __restrict__ batch,
                            float* gate, float* gmax, int n) {
  int wid = (blockIdx.x * blockDim.x + threadIdx.x) >> 6;
  int lane = threadIdx.x & 63;
  int nw = (gridDim.x * blockDim.x) >> 6;
  for (int i = wid; i < n; i += nw) {
    const float* up = u + (size_t)i * HD;
    float p = up[lane] * w2[lane] + up[64 + lane] * w2[64 + lane];
#pragma unroll
    for (int o = 32; o > 0; o >>= 1) p += __shfl_down(p, o);
    if (lane == 0) {
      float gv = p + b2[0];
      gate[i] = gv;
      atomicMaxFloat(&gmax[batch[i]], gv);
    }
  }
}

__global__ void exp_kernel(const float* __restrict__ gate, const int* __restrict__ batch,
                           const float* __restrict__ gmax, float* e, float* gsum, int n) {
  int idx = blockIdx.x * blockDim.x + threadIdx.x;
  if (idx < n) {
    int b = batch[idx];
    float evv = expf(gate[idx] - gmax[b]);
    e[idx] = evv;
    atomicAdd(&gsum[b], evv);
  }
}

__global__ void pool_kernel(const float* __restrict__ h, const float* __restrict__ e,
                            const float* __restrict__ gsum, const int* __restrict__ batch,
                            float* pooled, int n) {
  int gid = (blockIdx.x * blockDim.x + threadIdx.x) >> 5;
  int lane = threadIdx.x & 31;
  int ng = (gridDim.x * blockDim.x) >> 5;
  for (int i = gid; i < n; i += ng) {
    int b = batch[i];
    float alpha = e[i] / gsum[b];
    float4 v = *(const float4*)(h + (size_t)i * HD + lane * 4);
    float* p = pooled + (size_t)b * HD + lane * 4;
    atomicAdd(p + 0, alpha * v.x);
    atomicAdd(p + 1, alpha * v.y);
    atomicAdd(p + 2, alpha * v.z);
    atomicAdd(p + 3, alpha * v.w);
  }
}

// out[row] = relu(bn(zc[row])) @ W2 + b2 ; one 64-thread wave per row
__global__ void cls_out_kernel(const float* __restrict__ zc, const float* __restrict__ ab,
                               const float* __restrict__ W2, const float* __restrict__ b2,
                               float* out, int G) {
  int row = blockIdx.x;
  int t = threadIdx.x;
  float v0 = fmaxf(zc[(size_t)row * HD + t] * ab[t] + ab[HD + t], 0.f);
  float v1 = fmaxf(zc[(size_t)row * HD + 64 + t] * ab[64 + t] + ab[HD + 64 + t], 0.f);
  for (int o = 0; o < 10; o++) {
    float p = v0 * W2[t * 10 + o] + v1 * W2[(64 + t) * 10 + o];
#pragma unroll
    for (int s = 32; s > 0; s >>= 1) p += __shfl_down(p, s);
    if (t == 0) out[row * 10 + o] = p + b2[o];
  }
}

extern "C" void kernel_launch(void* const* d_in, const int* in_sizes, int n_in,
                              void* d_out, int out_size, void* d_ws, size_t ws_size,
                              hipStream_t stream) {
  const int* x     = (const int*)d_in[0];
  const int* ei    = (const int*)d_in[1];
  const int* batch = (const int*)d_in[2];
  const float* pe  = (const float*)d_in[4];
  const float* ce  = (const float*)d_in[5];
  const float* le  = (const float*)d_in[6];
  const float* cW1 = (const float*)d_in[7];
  const float* cb1 = (const float*)d_in[8];
  const float* cg1 = (const float*)d_in[9];
  const float* cbe1= (const float*)d_in[10];
  const float* cW2 = (const float*)d_in[11];
  const float* cb2 = (const float*)d_in[12];
  const float* ngm = (const float*)d_in[13];
  const float* nbe = (const float*)d_in[14];
  const float* gW1 = (const float*)d_in[15];
  const float* gb1 = (const float*)d_in[16];
  const float* gW2 = (const float*)d_in[17];
  const float* gb2 = (const float*)d_in[18];
  const float* clW1= (const float*)d_in[19];
  const float* clb1= (const float*)d_in[20];
  const float* clg = (const float*)d_in[21];
  const float* clbe= (const float*)d_in[22];
  const float* clW2= (const float*)d_in[23];
  const float* clb2= (const float*)d_in[24];

  int N = in_sizes[2];
  int E = in_sizes[1] / 2;
  int G = out_size / 10;

  float* buf0   = (float*)d_ws;              // h
  float* buf1   = buf0 + (size_t)N * HD;     // agg / z / u
  float* gate   = buf1 + (size_t)N * HD;
  float* ev     = gate + N;
  float* gmax   = ev + N;
  float* gsum   = gmax + G;
  float* pooled = gsum + G;
  float* zc     = pooled + (size_t)G * HD;
  float* stats  = zc + (size_t)G * HD;       // 7 * 256
  float* ab     = stats + 7 * 256;           // 7 * 256

  float* out = (float*)d_out;

  init_kernel<<<(G * HD + 255) / 256, 256, 0, stream>>>(gmax, gsum, pooled, stats, G);
  encode_kernel<<<2048, 256, 0, stream>>>(x, pe, ce, le, buf0, N);

  for (int l = 0; l < 3; l++) {
    hipMemsetAsync(buf1, 0, (size_t)N * HD * sizeof(float), stream);
    scatter_kernel<<<2048, 256, 0, stream>>>(buf0, ei, buf1, E);
    // z = (h + agg) @ W1 + b1   (in-place into buf1; row-safe: tile staged in LDS first)
    gemm128_kernel<true, false, false><<<N / 16, 256, 0, stream>>>(
        buf1, buf0, cW1 + (size_t)l * HD * HD, cb1 + l * HD, nullptr, buf1);
    stats_kernel<<<256, 256, 0, stream>>>(buf1, stats + l * 512, N);
    finalize_kernel<<<1, 128, 0, stream>>>(stats + l * 512, cg1 + l * HD, cbe1 + l * HD,
                                           ab + l * 512, 1.f / N);
    // z2 = relu(bn(z)) @ W2 + b2  -> buf0 (old h dead)
    gemm128_kernel<false, true, false><<<N / 16, 256, 0, stream>>>(
        buf1, nullptr, cW2 + (size_t)l * HD * HD, cb2 + l * HD, ab + l * 512, buf0);
    stats_kernel<<<256, 256, 0, stream>>>(buf0, stats + l * 512 + 256, N);
    finalize_kernel<<<1, 128, 0, stream>>>(stats + l * 512 + 256, ngm + l * HD, nbe + l * HD,
                                           ab + l * 512 + 256, 1.f / N);
    bnrelu_kernel<<<2048, 256, 0, stream>>>(buf0, ab + l * 512 + 256, N * HD);
  }

  // gate MLP: u = relu(h @ gate_W1 + gate_b1)
  gemm128_kernel<false, false, true><<<N / 16, 256, 0, stream>>>(
      buf0, nullptr, gW1, gb1, nullptr, buf1);
  gate_kernel<<<1024, 256, 0, stream>>>(buf1, gW2, gb2, batch, gate, gmax, N);
  exp_kernel<<<(N + 255) / 256, 256, 0, stream>>>(gate, batch, gmax, ev, gsum, N);
  pool_kernel<<<2048, 256, 0, stream>>>(buf0, ev, gsum, batch, pooled, N);

  // classifier
  gemm128_kernel<false, false, false><<<G / 16, 256, 0, stream>>>(
      pooled, nullptr, clW1, clb1, nullptr, zc);
  stats_kernel<<<64, 256, 0, stream>>>(zc, stats + 1536, G);
  finalize_kernel<<<1, 128, 0, stream>>>(stats + 1536, clg, clbe, ab + 1536, 1.f / G);
  cls_out_kernel<<<G, 64, 0, stream>>>(zc, ab + 1536, clW2, clb2, out, G);
}

// Round 2
// 2186.641 us; speedup vs baseline: 4.4360x; 4.4360x over previous
//
#include <hip/hip_runtime.h>
#include <math.h>

#define HD 128

__device__ __forceinline__ void atomicMaxFloat(float* addr, float val) {
  if (val >= 0.f) atomicMax((int*)addr, __float_as_int(val));
  else atomicMin((unsigned int*)addr, __float_as_uint(val));
}

__global__ void init_kernel(float* gmax, float* gsum, float* pooled, float* stats, int G) {
  int idx = blockIdx.x * blockDim.x + threadIdx.x;
  if (idx < G) { gmax[idx] = -INFINITY; gsum[idx] = 0.f; }
  if (idx < G * HD) pooled[idx] = 0.f;
  if (idx < 7 * 256) stats[idx] = 0.f;
}

__global__ void encode_kernel(const int* __restrict__ x, const float* __restrict__ pe,
                              const float* __restrict__ ce, const float* __restrict__ le,
                              float* __restrict__ h, int n) {
  int total = n * HD;
  int stride = gridDim.x * blockDim.x;
  for (int idx = blockIdx.x * blockDim.x + threadIdx.x; idx < total; idx += stride) {
    int node = idx >> 7, c = idx & (HD - 1);
    int lv = x[node * 3 + 0]; lv = lv < 0 ? 0 : (lv > 999 ? 999 : lv);
    int ct = x[node * 3 + 1]; ct = ct < 0 ? 0 : (ct > 4 ? 4 : ct);
    int th = x[node * 3 + 2]; th = th < 0 ? 0 : (th > 4999 ? 4999 : th);
    h[idx] = ce[ct * HD + c] + le[lv * HD + c] + pe[th * HD + c];
  }
}

// ---------------- CSR build (once per call; edge list reused for all 3 layers) ---

__global__ void zero_int(int* p, int n) {
  int stride = gridDim.x * blockDim.x;
  for (int i = blockIdx.x * blockDim.x + threadIdx.x; i < n; i += stride) p[i] = 0;
}

__global__ void hist_kernel(const int* __restrict__ ei, int* deg, int E) {
  int stride = gridDim.x * blockDim.x;
  for (int e = blockIdx.x * blockDim.x + threadIdx.x; e < E; e += stride)
    atomicAdd(&deg[ei[E + e]], 1);
}

#define SCAN_BS 1024
__global__ void scan1_kernel(const int* __restrict__ deg, int* __restrict__ off,
                             int* __restrict__ bsum, int n) {
  __shared__ int sh[256];
  int b = blockIdx.x, t = threadIdx.x;
  int base = b * SCAN_BS + t * 4;
  int v[4];
#pragma unroll
  for (int j = 0; j < 4; j++) v[j] = (base + j < n) ? deg[base + j] : 0;
  int s = v[0] + v[1] + v[2] + v[3];
  sh[t] = s;
  __syncthreads();
  for (int o = 1; o < 256; o <<= 1) {
    int x = (t >= o) ? sh[t - o] : 0;
    __syncthreads();
    sh[t] += x;
    __syncthreads();
  }
  int excl = sh[t] - s;
  if (t == 255) bsum[b] = sh[255];
  int run = excl;
#pragma unroll
  for (int j = 0; j < 4; j++) {
    if (base + j < n) off[base + j] = run;
    run += v[j];
  }
}

__global__ void scan2_kernel(int* bsum, int nb) {
  __shared__ int sh[128];
  int t = threadIdx.x;
  int v = (t < nb) ? bsum[t] : 0;
  sh[t] = v;
  __syncthreads();
  for (int o = 1; o < 128; o <<= 1) {
    int x = (t >= o) ? sh[t - o] : 0;
    __syncthreads();
    sh[t] += x;
    __syncthreads();
  }
  if (t < nb) bsum[t] = sh[t] - v;  // exclusive
}

__global__ void scan3_kernel(int* off, const int* __restrict__ bsum, int n, int E) {
  int idx = blockIdx.x * blockDim.x + threadIdx.x;
  int stride = gridDim.x * blockDim.x;
  for (int i = idx; i < n; i += stride) off[i] += bsum[i >> 10];
  if (idx == 0) off[n] = E;
}

__global__ void copy_int(const int* __restrict__ a, int* b, int n) {
  int stride = gridDim.x * blockDim.x;
  for (int i = blockIdx.x * blockDim.x + threadIdx.x; i < n; i += stride) b[i] = a[i];
}

__global__ void fill_kernel(const int* __restrict__ ei, int* cursor, int* csr_src, int E) {
  int stride = gridDim.x * blockDim.x;
  for (int e = blockIdx.x * blockDim.x + threadIdx.x; e < E; e += stride) {
    int s = ei[e];
    int d = ei[E + e];
    int pos = atomicAdd(&cursor[d], 1);
    csr_src[pos] = s;
  }
}

// out[i] = h[i] + sum_{e in CSR[i]} h[src[e]] ; one 32-lane group per node, float4/lane
__global__ void gather_kernel(const float* __restrict__ h, const int* __restrict__ off,
                              const int* __restrict__ src, float* __restrict__ out, int N) {
  int gid = (blockIdx.x * blockDim.x + threadIdx.x) >> 5;
  int lane = threadIdx.x & 31;
  int ng = (gridDim.x * blockDim.x) >> 5;
  for (int i = gid; i < N; i += ng) {
    int s0 = off[i], s1 = off[i + 1];
    float4 acc = *(const float4*)(h + (size_t)i * HD + lane * 4);
    for (int e = s0; e < s1; e++) {
      int s = src[e];
      float4 v = *(const float4*)(h + (size_t)s * HD + lane * 4);
      acc.x += v.x; acc.y += v.y; acc.z += v.z; acc.w += v.w;
    }
    *(float4*)(out + (size_t)i * HD + lane * 4) = acc;
  }
}

// ---------------- dense pieces -------------------------------------------------

// out[16 rows] = op(X [bn+relu]) @ W + bias ; W [128,128] row-major (k, c)
template<bool INBN, bool OUTRELU>
__global__ __launch_bounds__(256)
void gemm128_kernel(const float* X, const float* __restrict__ W,
                    const float* __restrict__ bias, const float* __restrict__ ab,
                    float* out) {
  __shared__ float Ws[64 * HD];
  __shared__ float Xs[16][132];
  int t = threadIdx.x;
  size_t base = (size_t)blockIdx.x * 16 * HD;

  for (int i = t * 4; i < 16 * HD; i += 1024) {
    float4 v = *(const float4*)(X + base + i);
    int cc = i & (HD - 1);
    if (INBN) {
      float4 a = *(const float4*)(ab + cc);
      float4 b = *(const float4*)(ab + HD + cc);
      v.x = fmaxf(v.x * a.x + b.x, 0.f);
      v.y = fmaxf(v.y * a.y + b.y, 0.f);
      v.z = fmaxf(v.z * a.z + b.z, 0.f);
      v.w = fmaxf(v.w * a.w + b.w, 0.f);
    }
    *(float4*)&Xs[i >> 7][cc] = v;
  }

  int cg = t & 15, r = t >> 4;
  float acc[8];
#pragma unroll
  for (int j = 0; j < 8; j++) acc[j] = bias[cg + j * 16];

  for (int half = 0; half < 2; half++) {
    __syncthreads();
    for (int i = t * 4; i < 64 * HD; i += 1024)
      *(float4*)&Ws[i] = *(const float4*)(W + half * 64 * HD + i);
    __syncthreads();
    int kb = half * 64;
    for (int k = 0; k < 64; k++) {
      float a = Xs[r][kb + k];
#pragma unroll
      for (int j = 0; j < 8; j++) acc[j] += a * Ws[k * HD + cg + j * 16];
    }
  }

  float* o = out + base + (size_t)r * HD;
#pragma unroll
  for (int j = 0; j < 8; j++) {
    float v = acc[j];
    if (OUTRELU) v = fmaxf(v, 0.f);
    o[cg + j * 16] = v;
  }
}

__global__ void stats_kernel(const float* __restrict__ z, float* stat, int n) {
  int c = threadIdx.x & (HD - 1);
  int rg = threadIdx.x >> 7;
  float s = 0.f, ss = 0.f;
  for (int r = blockIdx.x * 2 + rg; r < n; r += gridDim.x * 2) {
    float v = z[(size_t)r * HD + c];
    s += v; ss += v * v;
  }
  __shared__ float S[2][HD], SS[2][HD];
  S[rg][c] = s; SS[rg][c] = ss;
  __syncthreads();
  if (threadIdx.x < HD) {
    atomicAdd(&stat[c], S[0][c] + S[1][c]);
    atomicAdd(&stat[HD + c], SS[0][c] + SS[1][c]);
  }
}

__global__ void finalize_kernel(const float* __restrict__ stat, const float* __restrict__ g,
                                const float* __restrict__ be, float* ab, float inv_n) {
  int c = threadIdx.x;
  float mean = stat[c] * inv_n;
  float var = stat[HD + c] * inv_n - mean * mean;
  float inv = rsqrtf(var + 1e-5f);
  float a = inv * g[c];
  ab[c] = a;
  ab[HD + c] = be[c] - mean * a;
}

__global__ void bnrelu_kernel(float* z, const float* __restrict__ ab, int total) {
  int stride = gridDim.x * blockDim.x;
  for (int idx = blockIdx.x * blockDim.x + threadIdx.x; idx < total; idx += stride) {
    int c = idx & (HD - 1);
    z[idx] = fmaxf(z[idx] * ab[c] + ab[HD + c], 0.f);
  }
}

__global__ void gate_kernel(const float* __restrict__ u, const float* __restrict__ w2,
                            const float* __restrict__ b2, const int* __restrict__ batch,
                            float* gate, float* gmax, int n) {
  int wid = (blockIdx.x * blockDim.x + threadIdx.x) >> 6;
  int lane = threadIdx.x & 63;
  int nw = (gridDim.x * blockDim.x) >> 6;
  for (int i = wid; i < n; i += nw) {
    const float* up = u + (size_t)i * HD;
    float p = up[lane] * w2[lane] + up[64 + lane] * w2[64 + lane];
#pragma unroll
    for (int o = 32; o > 0; o >>= 1) p += __shfl_down(p, o);
    if (lane == 0) {
      float gv = p + b2[0];
      gate[i] = gv;
      atomicMaxFloat(&gmax[batch[i]], gv);
    }
  }
}

__global__ void exp_kernel(const float* __restrict__ gate, const int* __restrict__ batch,
                           const float* __restrict__ gmax, float* e, float* gsum, int n) {
  int idx = blockIdx.x * blockDim.x + threadIdx.x;
  if (idx < n) {
    int b = batch[idx];
    float evv = expf(gate[idx] - gmax[b]);
    e[idx] = evv;
    atomicAdd(&gsum[b], evv);
  }
}

__global__ void pool_kernel(const float* __restrict__ h, const float* __restrict__ e,
                            const float* __restrict__ gsum, const int* __restrict__ batch,
                            float* pooled, int n) {
  int gid = (blockIdx.x * blockDim.x + threadIdx.x) >> 5;
  int lane = threadIdx.x & 31;
  int ng = (gridDim.x * blockDim.x) >> 5;
  for (int i = gid; i < n; i += ng) {
    int b = batch[i];
    float alpha = e[i] / gsum[b];
    float4 v = *(const float4*)(h + (size_t)i * HD + lane * 4);
    float* p = pooled + (size_t)b * HD + lane * 4;
    atomicAdd(p + 0, alpha * v.x);
    atomicAdd(p + 1, alpha * v.y);
    atomicAdd(p + 2, alpha * v.z);
    atomicAdd(p + 3, alpha * v.w);
  }
}

__global__ void cls_out_kernel(const float* __restrict__ zc, const float* __restrict__ ab,
                               const float* __restrict__ W2, const float* __restrict__ b2,
                               float* out, int G) {
  int row = blockIdx.x;
  int t = threadIdx.x;
  float v0 = fmaxf(zc[(size_t)row * HD + t] * ab[t] + ab[HD + t], 0.f);
  float v1 = fmaxf(zc[(size_t)row * HD + 64 + t] * ab[64 + t] + ab[HD + 64 + t], 0.f);
  for (int o = 0; o < 10; o++) {
    float p = v0 * W2[t * 10 + o] + v1 * W2[(64 + t) * 10 + o];
#pragma unroll
    for (int s = 32; s > 0; s >>= 1) p += __shfl_down(p, s);
    if (t == 0) out[row * 10 + o] = p + b2[o];
  }
}

extern "C" void kernel_launch(void* const* d_in, const int* in_sizes, int n_in,
                              void* d_out, int out_size, void* d_ws, size_t ws_size,
                              hipStream_t stream) {
  const int* x     = (const int*)d_in[0];
  const int* ei    = (const int*)d_in[1];
  const int* batch = (const int*)d_in[2];
  const float* pe  = (const float*)d_in[4];
  const float* ce  = (const float*)d_in[5];
  const float* le  = (const float*)d_in[6];
  const float* cW1 = (const float*)d_in[7];
  const float* cb1 = (const float*)d_in[8];
  const float* cg1 = (const float*)d_in[9];
  const float* cbe1= (const float*)d_in[10];
  const float* cW2 = (const float*)d_in[11];
  const float* cb2 = (const float*)d_in[12];
  const float* ngm = (const float*)d_in[13];
  const float* nbe = (const float*)d_in[14];
  const float* gW1 = (const float*)d_in[15];
  const float* gb1 = (const float*)d_in[16];
  const float* gW2 = (const float*)d_in[17];
  const float* gb2 = (const float*)d_in[18];
  const float* clW1= (const float*)d_in[19];
  const float* clb1= (const float*)d_in[20];
  const float* clg = (const float*)d_in[21];
  const float* clbe= (const float*)d_in[22];
  const float* clW2= (const float*)d_in[23];
  const float* clb2= (const float*)d_in[24];

  int N = in_sizes[2];
  int E = in_sizes[1] / 2;
  int G = out_size / 10;

  float* buf0   = (float*)d_ws;              // h
  float* buf1   = buf0 + (size_t)N * HD;     // h+agg / z / u
  float* gate   = buf1 + (size_t)N * HD;
  float* ev     = gate + N;
  float* gmax   = ev + N;
  float* gsum   = gmax + G;
  float* pooled = gsum + G;
  float* zc     = pooled + (size_t)G * HD;
  float* stats  = zc + (size_t)G * HD;       // 7 * 256
  float* ab     = stats + 7 * 256;           // 7 * 256
  int* csr_off  = (int*)(ab + 7 * 256);      // N+1
  int* cursor   = csr_off + (N + 1);         // N
  int* bsum     = cursor + N;                // 128
  int* csr_src  = bsum + 128;                // E

  float* out = (float*)d_out;

  init_kernel<<<(G * HD + 255) / 256, 256, 0, stream>>>(gmax, gsum, pooled, stats, G);
  encode_kernel<<<2048, 256, 0, stream>>>(x, pe, ce, le, buf0, N);

  // ---- CSR build (dst-bucketed, reused by all 3 layers) ----
  int nb = (N + SCAN_BS - 1) / SCAN_BS;
  zero_int<<<256, 256, 0, stream>>>(cursor, N);
  hist_kernel<<<2048, 256, 0, stream>>>(ei, cursor, E);
  scan1_kernel<<<nb, 256, 0, stream>>>(cursor, csr_off, bsum, N);
  scan2_kernel<<<1, 128, 0, stream>>>(bsum, nb);
  scan3_kernel<<<256, 256, 0, stream>>>(csr_off, bsum, N, E);
  copy_int<<<256, 256, 0, stream>>>(csr_off, cursor, N);
  fill_kernel<<<2048, 256, 0, stream>>>(ei, cursor, csr_src, E);

  for (int l = 0; l < 3; l++) {
    // buf1 = h + agg  (gather, no atomics)
    gather_kernel<<<2048, 256, 0, stream>>>(buf0, csr_off, csr_src, buf1, N);
    // z = (h+agg) @ W1 + b1   (in-place; tile staged in LDS before stores)
    gemm128_kernel<false, false><<<N / 16, 256, 0, stream>>>(
        buf1, cW1 + (size_t)l * HD * HD, cb1 + l * HD, nullptr, buf1);
    stats_kernel<<<256, 256, 0, stream>>>(buf1, stats + l * 512, N);
    finalize_kernel<<<1, 128, 0, stream>>>(stats + l * 512, cg1 + l * HD, cbe1 + l * HD,
                                           ab + l * 512, 1.f / N);
    // z2 = relu(bn(z)) @ W2 + b2  -> buf0
    gemm128_kernel<true, false><<<N / 16, 256, 0, stream>>>(
        buf1, cW2 + (size_t)l * HD * HD, cb2 + l * HD, ab + l * 512, buf0);
    stats_kernel<<<256, 256, 0, stream>>>(buf0, stats + l * 512 + 256, N);
    finalize_kernel<<<1, 128, 0, stream>>>(stats + l * 512 + 256, ngm + l * HD, nbe + l * HD,
                                           ab + l * 512 + 256, 1.f / N);
    bnrelu_kernel<<<2048, 256, 0, stream>>>(buf0, ab + l * 512 + 256, N * HD);
  }

  // gate MLP: u = relu(h @ gate_W1 + gate_b1)
  gemm128_kernel<false, true><<<N / 16, 256, 0, stream>>>(buf0, gW1, gb1, nullptr, buf1);
  gate_kernel<<<1024, 256, 0, stream>>>(buf1, gW2, gb2, batch, gate, gmax, N);
  exp_kernel<<<(N + 255) / 256, 256, 0, stream>>>(gate, batch, gmax, ev, gsum, N);
  pool_kernel<<<2048, 256, 0, stream>>>(buf0, ev, gsum, batch, pooled, N);

  // classifier
  gemm128_kernel<false, false><<<G / 16, 256, 0, stream>>>(pooled, clW1, clb1, nullptr, zc);
  stats_kernel<<<64, 256, 0, stream>>>(zc, stats + 1536, G);
  finalize_kernel<<<1, 128, 0, stream>>>(stats + 1536, clg, clbe, ab + 1536, 1.f / G);
  cls_out_kernel<<<G, 64, 0, stream>>>(zc, ab + 1536, clW2, clb2, out, G);
}

// Round 3
// 1410.617 us; speedup vs baseline: 6.8764x; 1.5501x over previous
//
#include <hip/hip_runtime.h>
#include <math.h>

#define HD 128

__global__ void zero_f(float* p, int n) {
  int i = blockIdx.x * blockDim.x + threadIdx.x;
  if (i < n) p[i] = 0.f;
}

__global__ void encode_kernel(const int* __restrict__ x, const float* __restrict__ pe,
                              const float* __restrict__ ce, const float* __restrict__ le,
                              float* __restrict__ h, int n) {
  int total = n * HD;
  int stride = gridDim.x * blockDim.x;
  for (int idx = blockIdx.x * blockDim.x + threadIdx.x; idx < total; idx += stride) {
    int node = idx >> 7, c = idx & (HD - 1);
    int lv = x[node * 3 + 0]; lv = lv < 0 ? 0 : (lv > 999 ? 999 : lv);
    int ct = x[node * 3 + 1]; ct = ct < 0 ? 0 : (ct > 4 ? 4 : ct);
    int th = x[node * 3 + 2]; th = th < 0 ? 0 : (th > 4999 ? 4999 : th);
    h[idx] = ce[ct * HD + c] + le[lv * HD + c] + pe[th * HD + c];
  }
}

// ---------------- CSR build ----------------------------------------------------

__global__ void zero_int(int* p, int n) {
  int stride = gridDim.x * blockDim.x;
  for (int i = blockIdx.x * blockDim.x + threadIdx.x; i < n; i += stride) p[i] = 0;
}

__global__ void hist_kernel(const int* __restrict__ ei, int* deg, int E) {
  int stride = gridDim.x * blockDim.x;
  for (int e = blockIdx.x * blockDim.x + threadIdx.x; e < E; e += stride)
    atomicAdd(&deg[ei[E + e]], 1);
}

#define SCAN_BS 1024
__global__ void scan1_kernel(const int* __restrict__ deg, int* __restrict__ off,
                             int* __restrict__ bsum, int n) {
  __shared__ int sh[256];
  int b = blockIdx.x, t = threadIdx.x;
  int base = b * SCAN_BS + t * 4;
  int v[4];
#pragma unroll
  for (int j = 0; j < 4; j++) v[j] = (base + j < n) ? deg[base + j] : 0;
  int s = v[0] + v[1] + v[2] + v[3];
  sh[t] = s;
  __syncthreads();
  for (int o = 1; o < 256; o <<= 1) {
    int x = (t >= o) ? sh[t - o] : 0;
    __syncthreads();
    sh[t] += x;
    __syncthreads();
  }
  int excl = sh[t] - s;
  if (t == 255) bsum[b] = sh[255];
  int run = excl;
#pragma unroll
  for (int j = 0; j < 4; j++) {
    if (base + j < n) off[base + j] = run;
    run += v[j];
  }
}

__global__ void scan2_kernel(int* bsum, int nb) {
  __shared__ int sh[128];
  int t = threadIdx.x;
  int v = (t < nb) ? bsum[t] : 0;
  sh[t] = v;
  __syncthreads();
  for (int o = 1; o < 128; o <<= 1) {
    int x = (t >= o) ? sh[t - o] : 0;
    __syncthreads();
    sh[t] += x;
    __syncthreads();
  }
  if (t < nb) bsum[t] = sh[t] - v;
}

__global__ void scan3_kernel(int* off, const int* __restrict__ bsum, int n, int E) {
  int idx = blockIdx.x * blockDim.x + threadIdx.x;
  int stride = gridDim.x * blockDim.x;
  for (int i = idx; i < n; i += stride) off[i] += bsum[i >> 10];
  if (idx == 0) off[n] = E;
}

__global__ void copy_int(const int* __restrict__ a, int* b, int n) {
  int stride = gridDim.x * blockDim.x;
  for (int i = blockIdx.x * blockDim.x + threadIdx.x; i < n; i += stride) b[i] = a[i];
}

__global__ void fill_kernel(const int* __restrict__ ei, int* cursor, int* csr_src, int E) {
  int stride = gridDim.x * blockDim.x;
  for (int e = blockIdx.x * blockDim.x + threadIdx.x; e < E; e += stride) {
    int s = ei[e];
    int d = ei[E + e];
    int pos = atomicAdd(&cursor[d], 1);
    csr_src[pos] = s;
  }
}

// out[i] = f(h[i]) + sum f(h[src]); f = identity or relu(a*x+b) (deferred BN)
template<bool BN>
__global__ void gather_kernel(const float* __restrict__ h, const int* __restrict__ off,
                              const int* __restrict__ src, const float* __restrict__ ab,
                              float* __restrict__ out, int N) {
  int gid = (blockIdx.x * blockDim.x + threadIdx.x) >> 5;
  int lane = threadIdx.x & 31;
  int ng = (gridDim.x * blockDim.x) >> 5;
  float4 a4, b4;
  if (BN) {
    a4 = *(const float4*)(ab + lane * 4);
    b4 = *(const float4*)(ab + HD + lane * 4);
  }
  for (int i = gid; i < N; i += ng) {
    int s0 = off[i], s1 = off[i + 1];
    float4 acc = *(const float4*)(h + (size_t)i * HD + lane * 4);
    if (BN) {
      acc.x = fmaxf(acc.x * a4.x + b4.x, 0.f);
      acc.y = fmaxf(acc.y * a4.y + b4.y, 0.f);
      acc.z = fmaxf(acc.z * a4.z + b4.z, 0.f);
      acc.w = fmaxf(acc.w * a4.w + b4.w, 0.f);
    }
    for (int e = s0; e < s1; e++) {
      int s = src[e];
      float4 v = *(const float4*)(h + (size_t)s * HD + lane * 4);
      if (BN) {
        v.x = fmaxf(v.x * a4.x + b4.x, 0.f);
        v.y = fmaxf(v.y * a4.y + b4.y, 0.f);
        v.z = fmaxf(v.z * a4.z + b4.z, 0.f);
        v.w = fmaxf(v.w * a4.w + b4.w, 0.f);
      }
      acc.x += v.x; acc.y += v.y; acc.z += v.z; acc.w += v.w;
    }
    *(float4*)(out + (size_t)i * HD + lane * 4) = acc;
  }
}

// ---------------- big GEMM: out[Nx128] = f(X) @ W + bias -----------------------
// 128-row x 128-col block tile, 8x8 thread tile, K chunked by 32.
// INBN: f(x)=relu(ab0*x+ab1) applied to X during staging.
// GATE: skip out store; write gate[row] = sum_c relu(out[row][c]) * w2[c].
template<bool INBN, bool GATE>
__global__ __launch_bounds__(256, 4)
void gemm_big(const float* X, const float* __restrict__ W,
              const float* __restrict__ bias, const float* __restrict__ ab,
              const float* __restrict__ w2, float* out, float* gate, int Nn) {
  __shared__ float XsT[32][132];  // [k][row], padded
  __shared__ float Ws[32][HD];    // [k][col]
  int t = threadIdx.x;
  int r0 = (t >> 4) * 8;
  int c0 = (t & 15) * 8;
  long rowbase = (long)blockIdx.x * 128;

  float acc[8][8];
#pragma unroll
  for (int ci = 0; ci < 8; ci++) {
    float bv = bias[c0 + ci];
#pragma unroll
    for (int ri = 0; ri < 8; ri++) acc[ri][ci] = bv;
  }

  int sr = t >> 1;          // staging row 0..127
  int hf = t & 1;           // k-half
  long srow = rowbase + sr; if (srow > Nn - 1) srow = Nn - 1;
  const float* xrow = X + srow * HD;

  for (int k0 = 0; k0 < HD; k0 += 32) {
    __syncthreads();  // previous chunk consumed
    // stage W[32][128]
#pragma unroll
    for (int j = 0; j < 4; j++) {
      int i = j * 1024 + t * 4;
      int kk = i >> 7, c = i & (HD - 1);
      *(float4*)&Ws[kk][c] = *(const float4*)&W[(size_t)(k0 + kk) * HD + c];
    }
    // stage X transposed
#pragma unroll
    for (int j = 0; j < 4; j++) {
      int kc = k0 + hf * 16 + j * 4;
      float4 v = *(const float4*)&xrow[kc];
      if (INBN) {
        float4 a = *(const float4*)&ab[kc];
        float4 b = *(const float4*)&ab[HD + kc];
        v.x = fmaxf(v.x * a.x + b.x, 0.f);
        v.y = fmaxf(v.y * a.y + b.y, 0.f);
        v.z = fmaxf(v.z * a.z + b.z, 0.f);
        v.w = fmaxf(v.w * a.w + b.w, 0.f);
      }
      int kl = hf * 16 + j * 4;
      XsT[kl + 0][sr] = v.x;
      XsT[kl + 1][sr] = v.y;
      XsT[kl + 2][sr] = v.z;
      XsT[kl + 3][sr] = v.w;
    }
    __syncthreads();
#pragma unroll 8
    for (int kk = 0; kk < 32; kk++) {
      float4 a0 = *(float4*)&XsT[kk][r0];
      float4 a1 = *(float4*)&XsT[kk][r0 + 4];
      float4 b0 = *(float4*)&Ws[kk][c0];
      float4 b1 = *(float4*)&Ws[kk][c0 + 4];
      float ar[8] = {a0.x, a0.y, a0.z, a0.w, a1.x, a1.y, a1.z, a1.w};
      float bc[8] = {b0.x, b0.y, b0.z, b0.w, b1.x, b1.y, b1.z, b1.w};
#pragma unroll
      for (int ri = 0; ri < 8; ri++)
#pragma unroll
        for (int ci = 0; ci < 8; ci++) acc[ri][ci] += ar[ri] * bc[ci];
    }
  }

  if (GATE) {
    float w2v[8];
#pragma unroll
    for (int ci = 0; ci < 8; ci++) w2v[ci] = w2[c0 + ci];
#pragma unroll
    for (int ri = 0; ri < 8; ri++) {
      float p = 0.f;
#pragma unroll
      for (int ci = 0; ci < 8; ci++) p += fmaxf(acc[ri][ci], 0.f) * w2v[ci];
      p += __shfl_xor(p, 1, 16);
      p += __shfl_xor(p, 2, 16);
      p += __shfl_xor(p, 4, 16);
      p += __shfl_xor(p, 8, 16);
      long row = rowbase + r0 + ri;
      if ((t & 15) == 0 && row < Nn) gate[row] = p;
    }
  } else {
#pragma unroll
    for (int ri = 0; ri < 8; ri++) {
      long row = rowbase + r0 + ri;
      if (row < Nn) {
        float4 o0 = {acc[ri][0], acc[ri][1], acc[ri][2], acc[ri][3]};
        float4 o1 = {acc[ri][4], acc[ri][5], acc[ri][6], acc[ri][7]};
        *(float4*)&out[row * HD + c0] = o0;
        *(float4*)&out[row * HD + c0 + 4] = o1;
      }
    }
  }
}

__global__ void stats_kernel(const float* __restrict__ z, float* stat, int n) {
  int c = threadIdx.x & (HD - 1);
  int rg = threadIdx.x >> 7;
  float s = 0.f, ss = 0.f;
  for (int r = blockIdx.x * 2 + rg; r < n; r += gridDim.x * 2) {
    float v = z[(size_t)r * HD + c];
    s += v; ss += v * v;
  }
  __shared__ float S[2][HD], SS[2][HD];
  S[rg][c] = s; SS[rg][c] = ss;
  __syncthreads();
  if (threadIdx.x < HD) {
    atomicAdd(&stat[c], S[0][c] + S[1][c]);
    atomicAdd(&stat[HD + c], SS[0][c] + SS[1][c]);
  }
}

__global__ void finalize_kernel(const float* __restrict__ stat, const float* __restrict__ g,
                                const float* __restrict__ be, float* ab, float inv_n) {
  int c = threadIdx.x;
  float mean = stat[c] * inv_n;
  float var = stat[HD + c] * inv_n - mean * mean;
  float inv = rsqrtf(var + 1e-5f);
  float a = inv * g[c];
  ab[c] = a;
  ab[HD + c] = be[c] - mean * a;
}

// graph start offsets from sorted batch
__global__ void bound_kernel(const int* __restrict__ batch, int* gs, int N, int G) {
  int i = blockIdx.x * blockDim.x + threadIdx.x;
  if (i >= N) return;
  int b = batch[i];
  int prev = (i == 0) ? -1 : batch[i - 1];
  for (int g = prev + 1; g <= b; g++) gs[g] = i;
  if (i == N - 1)
    for (int g = b + 1; g <= G; g++) gs[g] = N;
}

// per-graph softmax-weighted pool over contiguous [gs[g], gs[g+1]) with deferred BN on h
__global__ void fused_pool(const float* __restrict__ h, const float* __restrict__ gate,
                           const int* __restrict__ gs, const float* __restrict__ ab,
                           float* __restrict__ pooled) {
  int g = blockIdx.x;
  int t = threadIdx.x;
  int s0 = gs[g], s1 = gs[g + 1];
  if (s0 >= s1) { pooled[(size_t)g * HD + t] = 0.f; return; }
  __shared__ float red[HD];
  float m = -INFINITY;
  for (int i = s0 + t; i < s1; i += HD) m = fmaxf(m, gate[i]);
  red[t] = m;
  __syncthreads();
  for (int o = 64; o > 0; o >>= 1) {
    if (t < o) red[t] = fmaxf(red[t], red[t + o]);
    __syncthreads();
  }
  m = red[0];
  __syncthreads();
  float s = 0.f;
  for (int i = s0 + t; i < s1; i += HD) s += expf(gate[i] - m);
  red[t] = s;
  __syncthreads();
  for (int o = 64; o > 0; o >>= 1) {
    if (t < o) red[t] += red[t + o];
    __syncthreads();
  }
  float inv = 1.f / red[0];
  float a = ab[t], b = ab[HD + t];
  float acc = 0.f;
  for (int i = s0; i < s1; i++) {
    float al = expf(gate[i] - m) * inv;
    float v = fmaxf(h[(size_t)i * HD + t] * a + b, 0.f);
    acc += al * v;
  }
  pooled[(size_t)g * HD + t] = acc;
}

__global__ void cls_out_kernel(const float* __restrict__ zc, const float* __restrict__ ab,
                               const float* __restrict__ W2, const float* __restrict__ b2,
                               float* out, int G) {
  int row = blockIdx.x;
  int t = threadIdx.x;
  float v0 = fmaxf(zc[(size_t)row * HD + t] * ab[t] + ab[HD + t], 0.f);
  float v1 = fmaxf(zc[(size_t)row * HD + 64 + t] * ab[64 + t] + ab[HD + 64 + t], 0.f);
  for (int o = 0; o < 10; o++) {
    float p = v0 * W2[t * 10 + o] + v1 * W2[(64 + t) * 10 + o];
#pragma unroll
    for (int s = 32; s > 0; s >>= 1) p += __shfl_down(p, s);
    if (t == 0) out[row * 10 + o] = p + b2[o];
  }
}

extern "C" void kernel_launch(void* const* d_in, const int* in_sizes, int n_in,
                              void* d_out, int out_size, void* d_ws, size_t ws_size,
                              hipStream_t stream) {
  const int* x     = (const int*)d_in[0];
  const int* ei    = (const int*)d_in[1];
  const int* batch = (const int*)d_in[2];
  const float* pe  = (const float*)d_in[4];
  const float* ce  = (const float*)d_in[5];
  const float* le  = (const float*)d_in[6];
  const float* cW1 = (const float*)d_in[7];
  const float* cb1 = (const float*)d_in[8];
  const float* cg1 = (const float*)d_in[9];
  const float* cbe1= (const float*)d_in[10];
  const float* cW2 = (const float*)d_in[11];
  const float* cb2 = (const float*)d_in[12];
  const float* ngm = (const float*)d_in[13];
  const float* nbe = (const float*)d_in[14];
  const float* gW1 = (const float*)d_in[15];
  const float* gb1 = (const float*)d_in[16];
  const float* gW2 = (const float*)d_in[17];
  const float* clW1= (const float*)d_in[19];
  const float* clb1= (const float*)d_in[20];
  const float* clg = (const float*)d_in[21];
  const float* clbe= (const float*)d_in[22];
  const float* clW2= (const float*)d_in[23];
  const float* clb2= (const float*)d_in[24];

  int N = in_sizes[2];
  int E = in_sizes[1] / 2;
  int G = out_size / 10;

  float* buf0   = (float*)d_ws;              // h / z2
  float* buf1   = buf0 + (size_t)N * HD;     // h+agg / z
  float* gate   = buf1 + (size_t)N * HD;
  float* pooled = gate + N;
  float* zc     = pooled + (size_t)G * HD;
  float* stats  = zc + (size_t)G * HD;       // 7 * 256
  float* ab     = stats + 7 * 256;           // 7 * 256
  int* csr_off  = (int*)(ab + 7 * 256);      // N+1
  int* cursor   = csr_off + (N + 1);         // N
  int* bsum     = cursor + N;                // 128
  int* gs       = bsum + 128;                // G+1
  int* csr_src  = gs + (G + 1);              // E

  float* out = (float*)d_out;
  int gemmBlocks = (N + 127) / 128;

  zero_f<<<7, 256, 0, stream>>>(stats, 7 * 256);
  encode_kernel<<<2048, 256, 0, stream>>>(x, pe, ce, le, buf0, N);

  // CSR build (reused by all 3 layers)
  int nb = (N + SCAN_BS - 1) / SCAN_BS;
  zero_int<<<256, 256, 0, stream>>>(cursor, N);
  hist_kernel<<<2048, 256, 0, stream>>>(ei, cursor, E);
  scan1_kernel<<<nb, 256, 0, stream>>>(cursor, csr_off, bsum, N);
  scan2_kernel<<<1, 128, 0, stream>>>(bsum, nb);
  scan3_kernel<<<256, 256, 0, stream>>>(csr_off, bsum, N, E);
  copy_int<<<256, 256, 0, stream>>>(csr_off, cursor, N);
  fill_kernel<<<2048, 256, 0, stream>>>(ei, cursor, csr_src, E);
  bound_kernel<<<(N + 255) / 256, 256, 0, stream>>>(batch, gs, N, G);

  for (int l = 0; l < 3; l++) {
    float* abPrev = ab + (l - 1) * 512 + 256;  // layer l-1 second BN (l>0)
    if (l == 0)
      gather_kernel<false><<<2048, 256, 0, stream>>>(buf0, csr_off, csr_src, nullptr, buf1, N);
    else
      gather_kernel<true><<<2048, 256, 0, stream>>>(buf0, csr_off, csr_src, abPrev, buf1, N);
    // z = (h+agg) @ W1 + b1  (in-place)
    gemm_big<false, false><<<gemmBlocks, 256, 0, stream>>>(
        buf1, cW1 + (size_t)l * HD * HD, cb1 + l * HD, nullptr, nullptr, buf1, nullptr, N);
    stats_kernel<<<256, 256, 0, stream>>>(buf1, stats + l * 512, N);
    finalize_kernel<<<1, 128, 0, stream>>>(stats + l * 512, cg1 + l * HD, cbe1 + l * HD,
                                           ab + l * 512, 1.f / N);
    // z2 = relu(bn1(z)) @ W2 + b2  -> buf0 (BN+ReLU deferred to consumers)
    gemm_big<true, false><<<gemmBlocks, 256, 0, stream>>>(
        buf1, cW2 + (size_t)l * HD * HD, cb2 + l * HD, ab + l * 512, nullptr, buf0, nullptr, N);
    stats_kernel<<<256, 256, 0, stream>>>(buf0, stats + l * 512 + 256, N);
    finalize_kernel<<<1, 128, 0, stream>>>(stats + l * 512 + 256, ngm + l * HD, nbe + l * HD,
                                           ab + l * 512 + 256, 1.f / N);
  }

  const float* abFin = ab + 2 * 512 + 256;  // layer-2 second BN (applied on read)
  // gate[i] = relu( relu(bn(z2)) @ gW1 + gb1 ) . gW2   (u never materialized; b2 cancels in softmax)
  gemm_big<true, true><<<gemmBlocks, 256, 0, stream>>>(
      buf0, gW1, gb1, abFin, gW2, nullptr, gate, N);
  fused_pool<<<G, HD, 0, stream>>>(buf0, gate, gs, abFin, pooled);

  // classifier
  gemm_big<false, false><<<(G + 127) / 128, 256, 0, stream>>>(
      pooled, clW1, clb1, nullptr, nullptr, zc, nullptr, G);
  stats_kernel<<<64, 256, 0, stream>>>(zc, stats + 1536, G);
  finalize_kernel<<<1, 128, 0, stream>>>(stats + 1536, clg, clbe, ab + 1536, 1.f / G);
  cls_out_kernel<<<G, 64, 0, stream>>>(zc, ab + 1536, clW2, clb2, out, G);
}

// Round 6
// 1119.778 us; speedup vs baseline: 8.6624x; 1.2597x over previous
//
#include <hip/hip_runtime.h>
#include <math.h>

#define HD 128

typedef __attribute__((ext_vector_type(8))) short bf16x8;
typedef __attribute__((ext_vector_type(8))) unsigned short us8;
typedef __attribute__((ext_vector_type(4))) unsigned short us4;
typedef __attribute__((ext_vector_type(4))) float f32x4;

__device__ __forceinline__ float bf2f(unsigned short u) {
  union { unsigned int i; float f; } v; v.i = ((unsigned int)u) << 16; return v.f;
}
__device__ __forceinline__ unsigned short f2bf(float f) {
  union { float f; unsigned int i; } v; v.f = f;
  unsigned int u = v.i;
  u += 0x7FFFu + ((u >> 16) & 1u);
  return (unsigned short)(u >> 16);
}

__global__ void zero_f(float* p, int n) {
  int i = blockIdx.x * blockDim.x + threadIdx.x;
  if (i < n) p[i] = 0.f;
}

__global__ void zero_int(int* p, int n) {
  int stride = gridDim.x * blockDim.x;
  for (int i = blockIdx.x * blockDim.x + threadIdx.x; i < n; i += stride) p[i] = 0;
}

__global__ void encode_kernel(const int* __restrict__ x, const float* __restrict__ pe,
                              const float* __restrict__ ce, const float* __restrict__ le,
                              float* __restrict__ h, int n) {
  int total = n * HD;
  int stride = gridDim.x * blockDim.x;
  for (int idx = blockIdx.x * blockDim.x + threadIdx.x; idx < total; idx += stride) {
    int node = idx >> 7, c = idx & (HD - 1);
    int lv = x[node * 3 + 0]; lv = lv < 0 ? 0 : (lv > 999 ? 999 : lv);
    int ct = x[node * 3 + 1]; ct = ct < 0 ? 0 : (ct > 4 ? 4 : ct);
    int th = x[node * 3 + 2]; th = th < 0 ? 0 : (th > 4999 ? 4999 : th);
    h[idx] = ce[ct * HD + c] + le[lv * HD + c] + pe[th * HD + c];
  }
}

// split 7 [128][128] f32 weight mats into bf16 hi/lo, transposed [c][k], pre-swizzled
// dest index: c*HD + ((g ^ (c&7))<<3) + (k&7), g = k>>3
__global__ void prep_w(const float* __restrict__ cW1, const float* __restrict__ cW2,
                       const float* __restrict__ gW1,
                       unsigned short* __restrict__ whi, unsigned short* __restrict__ wlo) {
  int m = blockIdx.x;
  const float* W = (m < 3) ? cW1 + (size_t)m * HD * HD
                 : (m < 6) ? cW2 + (size_t)(m - 3) * HD * HD : gW1;
  unsigned short* oh = whi + (size_t)m * HD * HD;
  unsigned short* ol = wlo + (size_t)m * HD * HD;
  for (int i = threadIdx.x; i < HD * HD; i += 256) {
    int k = i >> 7, c = i & (HD - 1);
    float f = W[i];
    unsigned short hh = f2bf(f);
    unsigned short ll = f2bf(f - bf2f(hh));
    int g = k >> 3;
    int d = c * HD + (((g ^ (c & 7)) << 3) | (k & 7));
    oh[d] = hh;
    ol[d] = ll;
  }
}

// ---------------- CSR build ----------------------------------------------------

__global__ void hist_kernel(const int* __restrict__ ei, int* deg, int E) {
  int stride = gridDim.x * blockDim.x;
  for (int e = blockIdx.x * blockDim.x + threadIdx.x; e < E; e += stride)
    atomicAdd(&deg[ei[E + e]], 1);
}

#define SCAN_BS 1024
__global__ void scan1_kernel(const int* __restrict__ deg, int* __restrict__ off,
                             int* __restrict__ bsum, int n) {
  __shared__ int sh[256];
  int b = blockIdx.x, t = threadIdx.x;
  int base = b * SCAN_BS + t * 4;
  int v[4];
#pragma unroll
  for (int j = 0; j < 4; j++) v[j] = (base + j < n) ? deg[base + j] : 0;
  int s = v[0] + v[1] + v[2] + v[3];
  sh[t] = s;
  __syncthreads();
  for (int o = 1; o < 256; o <<= 1) {
    int x = (t >= o) ? sh[t - o] : 0;
    __syncthreads();
    sh[t] += x;
    __syncthreads();
  }
  int excl = sh[t] - s;
  if (t == 255) bsum[b] = sh[255];
  int run = excl;
#pragma unroll
  for (int j = 0; j < 4; j++) {
    if (base + j < n) off[base + j] = run;
    run += v[j];
  }
}

__global__ void scan2_kernel(int* bsum, int nb) {
  __shared__ int sh[128];
  int t = threadIdx.x;
  int v = (t < nb) ? bsum[t] : 0;
  sh[t] = v;
  __syncthreads();
  for (int o = 1; o < 128; o <<= 1) {
    int x = (t >= o) ? sh[t - o] : 0;
    __syncthreads();
    sh[t] += x;
    __syncthreads();
  }
  if (t < nb) bsum[t] = sh[t] - v;
}

__global__ void scan3_kernel(int* off, const int* __restrict__ bsum, int n, int E) {
  int idx = blockIdx.x * blockDim.x + threadIdx.x;
  int stride = gridDim.x * blockDim.x;
  for (int i = idx; i < n; i += stride) off[i] += bsum[i >> 10];
  if (idx == 0) off[n] = E;
}

__global__ void copy_int(const int* __restrict__ a, int* b, int n) {
  int stride = gridDim.x * blockDim.x;
  for (int i = blockIdx.x * blockDim.x + threadIdx.x; i < n; i += stride) b[i] = a[i];
}

__global__ void fill_kernel(const int* __restrict__ ei, int* cursor, int* csr_src, int E) {
  int stride = gridDim.x * blockDim.x;
  for (int e = blockIdx.x * blockDim.x + threadIdx.x; e < E; e += stride) {
    int s = ei[e];
    int d = ei[E + e];
    int pos = atomicAdd(&cursor[d], 1);
    csr_src[pos] = s;
  }
}

// out[i] = f(h[i]) + sum f(h[src]); f = identity or relu(a*x+b); f32
template<bool BN>
__global__ void gather_kernel(const float* __restrict__ h, const int* __restrict__ off,
                              const int* __restrict__ src, const float* __restrict__ ab,
                              float* __restrict__ out, int N) {
  int gid = (blockIdx.x * blockDim.x + threadIdx.x) >> 5;
  int lane = threadIdx.x & 31;
  int ng = (gridDim.x * blockDim.x) >> 5;
  float4 a4, b4;
  if (BN) {
    a4 = *(const float4*)(ab + lane * 4);
    b4 = *(const float4*)(ab + HD + lane * 4);
  }
  for (int i = gid; i < N; i += ng) {
    int s0 = off[i], s1 = off[i + 1];
    float4 acc = *(const float4*)(h + (size_t)i * HD + lane * 4);
    if (BN) {
      acc.x = fmaxf(acc.x * a4.x + b4.x, 0.f);
      acc.y = fmaxf(acc.y * a4.y + b4.y, 0.f);
      acc.z = fmaxf(acc.z * a4.z + b4.z, 0.f);
      acc.w = fmaxf(acc.w * a4.w + b4.w, 0.f);
    }
    for (int e = s0; e < s1; e++) {
      int s = src[e];
      float4 v = *(const float4*)(h + (size_t)s * HD + lane * 4);
      if (BN) {
        v.x = fmaxf(v.x * a4.x + b4.x, 0.f);
        v.y = fmaxf(v.y * a4.y + b4.y, 0.f);
        v.z = fmaxf(v.z * a4.z + b4.z, 0.f);
        v.w = fmaxf(v.w * a4.w + b4.w, 0.f);
      }
      acc.x += v.x; acc.y += v.y; acc.z += v.z; acc.w += v.w;
    }
    *(float4*)(out + (size_t)i * HD + lane * 4) = acc;
  }
}

// ---------------- split-bf16 MFMA GEMM -----------------------------------------
// out[128 x 128] = f(X_f32) @ W^T + bias via A*B ~= Ah*Bh + Ah*Bl + Al*Bh.
// f32 in/out; inputs split to bf16 hi/lo at stage time (BN+ReLU applied in f32 first).
// 512 threads (8 waves), K=128 staged once; XOR-swizzled 16B granules.
template<bool INBN, bool GATE, bool STATS>
__global__ __launch_bounds__(512, 1)
void gemm_split(const float* __restrict__ X, const unsigned short* __restrict__ Whi,
                const unsigned short* __restrict__ Wlo,
                const float* __restrict__ bias, const float* __restrict__ ab,
                const float* __restrict__ w2, float* __restrict__ outf,
                float* __restrict__ gate, float* __restrict__ stat, int Nn) {
  __shared__ unsigned short XsH[128 * HD];
  __shared__ unsigned short XsL[128 * HD];
  __shared__ unsigned short WsH[HD * HD];
  __shared__ unsigned short WsL[HD * HD];
  __shared__ float red[2 * HD];
  int t = threadIdx.x;
  long rowbase = (long)blockIdx.x * 128;

  // stage X: split f32 -> hi/lo bf16 (128 rows x 128 k)
#pragma unroll
  for (int it = 0; it < 8; it++) {
    int i = (t + it * 512) * 4;
    int r = i >> 7, k = i & (HD - 1);
    long row = rowbase + r; if (row > Nn - 1) row = Nn - 1;
    float4 v = *(const float4*)(X + row * HD + k);
    float f[4] = {v.x, v.y, v.z, v.w};
    if (INBN) {
#pragma unroll
      for (int j = 0; j < 4; j++)
        f[j] = fmaxf(f[j] * ab[k + j] + ab[HD + k + j], 0.f);
    }
    us4 hi, lo;
#pragma unroll
    for (int j = 0; j < 4; j++) {
      unsigned short hh = f2bf(f[j]);
      hi[j] = hh;
      lo[j] = f2bf(f[j] - bf2f(hh));
    }
    int g = k >> 3;
    int off = r * HD + ((((g ^ (r & 7)) << 3)) | (k & 7));
    *(us4*)(XsH + off) = hi;
    *(us4*)(XsL + off) = lo;
  }
  // stage W hi/lo (pre-swizzled by prep_w): straight copies
#pragma unroll
  for (int it = 0; it < 4; it++) {
    int i = (t + it * 512) * 8;
    *(us8*)(WsH + i) = *(const us8*)(Whi + i);
    *(us8*)(WsL + i) = *(const us8*)(Wlo + i);
  }
  if (STATS && t < 2 * HD) red[t] = 0.f;
  __syncthreads();

  int w = t >> 6, l = t & 63;
  int lr = l & 15, lg = l >> 4;

  f32x4 acc[8];
#pragma unroll
  for (int ct = 0; ct < 8; ct++) acc[ct] = (f32x4){0.f, 0.f, 0.f, 0.f};

  bf16x8 aH[4], aL[4];
  int arow = w * 16 + lr;
#pragma unroll
  for (int k4 = 0; k4 < 4; k4++) {
    int kg = k4 * 4 + lg;
    int off = arow * HD + (((kg ^ (arow & 7)) << 3));
    aH[k4] = *(bf16x8*)(XsH + off);
    aL[k4] = *(bf16x8*)(XsL + off);
  }
#pragma unroll
  for (int ct = 0; ct < 8; ct++) {
    int c = ct * 16 + lr;
#pragma unroll
    for (int k4 = 0; k4 < 4; k4++) {
      int kg = k4 * 4 + lg;
      int off = c * HD + (((kg ^ (c & 7)) << 3));
      bf16x8 bH = *(bf16x8*)(WsH + off);
      bf16x8 bL = *(bf16x8*)(WsL + off);
      acc[ct] = __builtin_amdgcn_mfma_f32_16x16x32_bf16(aH[k4], bH, acc[ct], 0, 0, 0);
      acc[ct] = __builtin_amdgcn_mfma_f32_16x16x32_bf16(aH[k4], bL, acc[ct], 0, 0, 0);
      acc[ct] = __builtin_amdgcn_mfma_f32_16x16x32_bf16(aL[k4], bH, acc[ct], 0, 0, 0);
    }
  }

  // D layout: row_in_blk = w*16 + lg*4 + jj, col = ct*16 + lr
  if (GATE) {
#pragma unroll
    for (int jj = 0; jj < 4; jj++) {
      float p = 0.f;
#pragma unroll
      for (int ct = 0; ct < 8; ct++) {
        float v = fmaxf(acc[ct][jj] + bias[ct * 16 + lr], 0.f);
        p += v * w2[ct * 16 + lr];
      }
      p += __shfl_xor(p, 1);
      p += __shfl_xor(p, 2);
      p += __shfl_xor(p, 4);
      p += __shfl_xor(p, 8);
      long row = rowbase + w * 16 + lg * 4 + jj;
      if (lr == 0 && row < Nn) gate[row] = p;
    }
  } else {
    float s[8], ss[8];
#pragma unroll
    for (int ct = 0; ct < 8; ct++) { s[ct] = 0.f; ss[ct] = 0.f; }
#pragma unroll
    for (int jj = 0; jj < 4; jj++) {
      long row = rowbase + w * 16 + lg * 4 + jj;
      bool ok = row < Nn;
#pragma unroll
      for (int ct = 0; ct < 8; ct++) {
        float v = acc[ct][jj] + bias[ct * 16 + lr];
        if (ok) {
          outf[row * HD + ct * 16 + lr] = v;
          if (STATS) { s[ct] += v; ss[ct] += v * v; }
        }
      }
    }
    if (STATS) {
#pragma unroll
      for (int ct = 0; ct < 8; ct++) {
        float sv = s[ct], sq = ss[ct];
        sv += __shfl_xor(sv, 16); sq += __shfl_xor(sq, 16);
        sv += __shfl_xor(sv, 32); sq += __shfl_xor(sq, 32);
        if (lg == 0) {
          atomicAdd(&red[ct * 16 + lr], sv);
          atomicAdd(&red[HD + ct * 16 + lr], sq);
        }
      }
      __syncthreads();
      float* st = stat + (blockIdx.x & 3) * 256;
      if (t < HD) {
        atomicAdd(&st[t], red[t]);
        atomicAdd(&st[HD + t], red[HD + t]);
      }
    }
  }
}

// 4-replica stats -> ab
__global__ void finalize_kernel(const float* __restrict__ stat, const float* __restrict__ g,
                                const float* __restrict__ be, float* ab, float inv_n) {
  int c = threadIdx.x;
  float s = stat[c] + stat[256 + c] + stat[512 + c] + stat[768 + c];
  float sq = stat[HD + c] + stat[256 + HD + c] + stat[512 + HD + c] + stat[768 + HD + c];
  float mean = s * inv_n;
  float var = sq * inv_n - mean * mean;
  float inv = rsqrtf(var + 1e-5f);
  float a = inv * g[c];
  ab[c] = a;
  ab[HD + c] = be[c] - mean * a;
}

__global__ void finalize1_kernel(const float* __restrict__ stat, const float* __restrict__ g,
                                 const float* __restrict__ be, float* ab, float inv_n) {
  int c = threadIdx.x;
  float mean = stat[c] * inv_n;
  float var = stat[HD + c] * inv_n - mean * mean;
  float inv = rsqrtf(var + 1e-5f);
  float a = inv * g[c];
  ab[c] = a;
  ab[HD + c] = be[c] - mean * a;
}

__global__ void bound_kernel(const int* __restrict__ batch, int* gs, int N, int G) {
  int i = blockIdx.x * blockDim.x + threadIdx.x;
  if (i >= N) return;
  int b = batch[i];
  int prev = (i == 0) ? -1 : batch[i - 1];
  for (int g = prev + 1; g <= b; g++) gs[g] = i;
  if (i == N - 1)
    for (int g = b + 1; g <= G; g++) gs[g] = N;
}

// per-graph softmax pool over contiguous [gs[g], gs[g+1]) with deferred BN on h; f32
__global__ void fused_pool(const float* __restrict__ h, const float* __restrict__ gate,
                           const int* __restrict__ gs, const float* __restrict__ ab,
                           float* __restrict__ pooled) {
  int g = blockIdx.x;
  int t = threadIdx.x;
  int s0 = gs[g], s1 = gs[g + 1];
  if (s0 >= s1) { pooled[(size_t)g * HD + t] = 0.f; return; }
  __shared__ float red[HD];
  float m = -INFINITY;
  for (int i = s0 + t; i < s1; i += HD) m = fmaxf(m, gate[i]);
  red[t] = m;
  __syncthreads();
  for (int o = 64; o > 0; o >>= 1) {
    if (t < o) red[t] = fmaxf(red[t], red[t + o]);
    __syncthreads();
  }
  m = red[0];
  __syncthreads();
  float s = 0.f;
  for (int i = s0 + t; i < s1; i += HD) s += expf(gate[i] - m);
  red[t] = s;
  __syncthreads();
  for (int o = 64; o > 0; o >>= 1) {
    if (t < o) red[t] += red[t + o];
    __syncthreads();
  }
  float inv = 1.f / red[0];
  float a = ab[t], b = ab[HD + t];
  float acc = 0.f;
  for (int i = s0; i < s1; i++) {
    float al = expf(gate[i] - m) * inv;
    float v = fmaxf(h[(size_t)i * HD + t] * a + b, 0.f);
    acc += al * v;
  }
  pooled[(size_t)g * HD + t] = acc;
}

// f32 classifier GEMM: zc[G x 128] = pooled @ W + bias
__global__ __launch_bounds__(256, 4)
void gemm_f32(const float* __restrict__ X, const float* __restrict__ W,
              const float* __restrict__ bias, float* __restrict__ out, int Nn) {
  __shared__ float XsT[32][132];
  __shared__ float Ws[32][HD];
  int t = threadIdx.x;
  int r0 = (t >> 4) * 8;
  int c0 = (t & 15) * 8;
  long rowbase = (long)blockIdx.x * 128;

  float acc[8][8];
#pragma unroll
  for (int ci = 0; ci < 8; ci++) {
    float bv = bias[c0 + ci];
#pragma unroll
    for (int ri = 0; ri < 8; ri++) acc[ri][ci] = bv;
  }

  int sr = t >> 1;
  int hf = t & 1;
  long srow = rowbase + sr; if (srow > Nn - 1) srow = Nn - 1;
  const float* xrow = X + srow * HD;

  for (int k0 = 0; k0 < HD; k0 += 32) {
    __syncthreads();
#pragma unroll
    for (int j = 0; j < 4; j++) {
      int i = j * 1024 + t * 4;
      int kk = i >> 7, c = i & (HD - 1);
      *(float4*)&Ws[kk][c] = *(const float4*)&W[(size_t)(k0 + kk) * HD + c];
    }
#pragma unroll
    for (int j = 0; j < 4; j++) {
      int kc = k0 + hf * 16 + j * 4;
      float4 v = *(const float4*)&xrow[kc];
      int kl = hf * 16 + j * 4;
      XsT[kl + 0][sr] = v.x;
      XsT[kl + 1][sr] = v.y;
      XsT[kl + 2][sr] = v.z;
      XsT[kl + 3][sr] = v.w;
    }
    __syncthreads();
#pragma unroll 8
    for (int kk = 0; kk < 32; kk++) {
      float4 a0 = *(float4*)&XsT[kk][r0];
      float4 a1 = *(float4*)&XsT[kk][r0 + 4];
      float4 b0 = *(float4*)&Ws[kk][c0];
      float4 b1 = *(float4*)&Ws[kk][c0 + 4];
      float ar[8] = {a0.x, a0.y, a0.z, a0.w, a1.x, a1.y, a1.z, a1.w};
      float bc[8] = {b0.x, b0.y, b0.z, b0.w, b1.x, b1.y, b1.z, b1.w};
#pragma unroll
      for (int ri = 0; ri < 8; ri++)
#pragma unroll
        for (int ci = 0; ci < 8; ci++) acc[ri][ci] += ar[ri] * bc[ci];
    }
  }

#pragma unroll
  for (int ri = 0; ri < 8; ri++) {
    long row = rowbase + r0 + ri;
    if (row < Nn) {
      float4 o0 = {acc[ri][0], acc[ri][1], acc[ri][2], acc[ri][3]};
      float4 o1 = {acc[ri][4], acc[ri][5], acc[ri][6], acc[ri][7]};
      *(float4*)&out[row * HD + c0] = o0;
      *(float4*)&out[row * HD + c0 + 4] = o1;
    }
  }
}

__global__ void stats_f32(const float* __restrict__ z, float* stat, int n) {
  int c = threadIdx.x & (HD - 1);
  int rg = threadIdx.x >> 7;
  float s = 0.f, ss = 0.f;
  for (int r = blockIdx.x * 2 + rg; r < n; r += gridDim.x * 2) {
    float v = z[(size_t)r * HD + c];
    s += v; ss += v * v;
  }
  __shared__ float S[2][HD], SS[2][HD];
  S[rg][c] = s; SS[rg][c] = ss;
  __syncthreads();
  if (threadIdx.x < HD) {
    atomicAdd(&stat[c], S[0][c] + S[1][c]);
    atomicAdd(&stat[HD + c], SS[0][c] + SS[1][c]);
  }
}

__global__ void cls_out_kernel(const float* __restrict__ zc, const float* __restrict__ ab,
                               const float* __restrict__ W2, const float* __restrict__ b2,
                               float* out, int G) {
  int row = blockIdx.x;
  int t = threadIdx.x;
  float v0 = fmaxf(zc[(size_t)row * HD + t] * ab[t] + ab[HD + t], 0.f);
  float v1 = fmaxf(zc[(size_t)row * HD + 64 + t] * ab[64 + t] + ab[HD + 64 + t], 0.f);
  for (int o = 0; o < 10; o++) {
    float p = v0 * W2[t * 10 + o] + v1 * W2[(64 + t) * 10 + o];
#pragma unroll
    for (int s = 32; s > 0; s >>= 1) p += __shfl_down(p, s);
    if (t == 0) out[row * 10 + o] = p + b2[o];
  }
}

extern "C" void kernel_launch(void* const* d_in, const int* in_sizes, int n_in,
                              void* d_out, int out_size, void* d_ws, size_t ws_size,
                              hipStream_t stream) {
  const int* x     = (const int*)d_in[0];
  const int* ei    = (const int*)d_in[1];
  const int* batch = (const int*)d_in[2];
  const float* pe  = (const float*)d_in[4];
  const float* ce  = (const float*)d_in[5];
  const float* le  = (const float*)d_in[6];
  const float* cW1 = (const float*)d_in[7];
  const float* cb1 = (const float*)d_in[8];
  const float* cg1 = (const float*)d_in[9];
  const float* cbe1= (const float*)d_in[10];
  const float* cW2 = (const float*)d_in[11];
  const float* cb2 = (const float*)d_in[12];
  const float* ngm = (const float*)d_in[13];
  const float* nbe = (const float*)d_in[14];
  const float* gW1 = (const float*)d_in[15];
  const float* gb1 = (const float*)d_in[16];
  const float* gW2 = (const float*)d_in[17];
  const float* clW1= (const float*)d_in[19];
  const float* clb1= (const float*)d_in[20];
  const float* clg = (const float*)d_in[21];
  const float* clbe= (const float*)d_in[22];
  const float* clW2= (const float*)d_in[23];
  const float* clb2= (const float*)d_in[24];

  int N = in_sizes[2];
  int E = in_sizes[1] / 2;
  int G = out_size / 10;

  float* buf0   = (float*)d_ws;              // h (f32)
  float* buf1   = buf0 + (size_t)N * HD;     // h+agg / z (f32)
  float* pooled = buf1 + (size_t)N * HD;     // G x 128
  float* gate   = pooled + (size_t)G * HD;   // N
  float* zc     = gate + N;                  // G x 128
  float* stats  = zc + (size_t)G * HD;       // 7 x 1024
  float* ab     = stats + 7 * 1024;          // 7 x 256
  unsigned short* whi = (unsigned short*)(ab + 7 * 256);  // 7 x 128 x 128 bf16
  unsigned short* wlo = whi + 7 * HD * HD;
  int* csr_off  = (int*)(wlo + 7 * HD * HD); // N+1
  int* cursor   = csr_off + (N + 1);         // N
  int* bsum     = cursor + N;                // 128
  int* gs       = bsum + 128;                // G+1
  int* csr_src  = gs + (G + 1);              // E

  float* out = (float*)d_out;
  int gemmBlocks = (N + 127) / 128;

  zero_f<<<28, 256, 0, stream>>>(stats, 7 * 1024);
  encode_kernel<<<2048, 256, 0, stream>>>(x, pe, ce, le, buf0, N);
  prep_w<<<7, 256, 0, stream>>>(cW1, cW2, gW1, whi, wlo);

  // CSR build (reused by all 3 layers)
  int nb = (N + SCAN_BS - 1) / SCAN_BS;
  zero_int<<<256, 256, 0, stream>>>(cursor, N);
  hist_kernel<<<2048, 256, 0, stream>>>(ei, cursor, E);
  scan1_kernel<<<nb, 256, 0, stream>>>(cursor, csr_off, bsum, N);
  scan2_kernel<<<1, 128, 0, stream>>>(bsum, nb);
  scan3_kernel<<<256, 256, 0, stream>>>(csr_off, bsum, N, E);
  copy_int<<<256, 256, 0, stream>>>(csr_off, cursor, N);
  fill_kernel<<<2048, 256, 0, stream>>>(ei, cursor, csr_src, E);
  bound_kernel<<<(N + 255) / 256, 256, 0, stream>>>(batch, gs, N, G);

  for (int l = 0; l < 3; l++) {
    float* abPrev = ab + (l - 1) * 512 + 256;
    if (l == 0)
      gather_kernel<false><<<2048, 256, 0, stream>>>(buf0, csr_off, csr_src, nullptr, buf1, N);
    else
      gather_kernel<true><<<2048, 256, 0, stream>>>(buf0, csr_off, csr_src, abPrev, buf1, N);
    // z = (h+agg) @ W1 + b1 (in-place, f32) + fused stats
    gemm_split<false, false, true><<<gemmBlocks, 512, 0, stream>>>(
        buf1, whi + (size_t)l * HD * HD, wlo + (size_t)l * HD * HD,
        cb1 + l * HD, nullptr, nullptr, buf1, nullptr, stats + l * 2048, N);
    finalize_kernel<<<1, 128, 0, stream>>>(stats + l * 2048, cg1 + l * HD, cbe1 + l * HD,
                                           ab + l * 512, 1.f / N);
    // z2 = relu(bn1(z)) @ W2 + b2 -> buf0 + fused stats
    gemm_split<true, false, true><<<gemmBlocks, 512, 0, stream>>>(
        buf1, whi + (size_t)(3 + l) * HD * HD, wlo + (size_t)(3 + l) * HD * HD,
        cb2 + l * HD, ab + l * 512, nullptr, buf0, nullptr, stats + l * 2048 + 1024, N);
    finalize_kernel<<<1, 128, 0, stream>>>(stats + l * 2048 + 1024, ngm + l * HD, nbe + l * HD,
                                           ab + l * 512 + 256, 1.f / N);
  }

  const float* abFin = ab + 2 * 512 + 256;
  // gate[i] = relu( relu(bn(h3)) @ gW1 + gb1 ) . gW2  (b2 cancels in softmax)
  gemm_split<true, true, false><<<gemmBlocks, 512, 0, stream>>>(
      buf0, whi + (size_t)6 * HD * HD, wlo + (size_t)6 * HD * HD,
      gb1, abFin, gW2, nullptr, gate, nullptr, N);
  fused_pool<<<G, HD, 0, stream>>>(buf0, gate, gs, abFin, pooled);

  // classifier tail in f32
  gemm_f32<<<(G + 127) / 128, 256, 0, stream>>>(pooled, clW1, clb1, zc, G);
  stats_f32<<<64, 256, 0, stream>>>(zc, stats + 6 * 1024, G);
  finalize1_kernel<<<1, 128, 0, stream>>>(stats + 6 * 1024, clg, clbe, ab + 6 * 256, 1.f / G);
  cls_out_kernel<<<G, 64, 0, stream>>>(zc, ab + 6 * 256, clW2, clb2, out, G);
}

// Round 7
// 1051.927 us; speedup vs baseline: 9.2212x; 1.0645x over previous
//
#include <hip/hip_runtime.h>
#include <math.h>

#define HD 128

typedef __attribute__((ext_vector_type(8))) short bf16x8;
typedef __attribute__((ext_vector_type(8))) unsigned short us8;
typedef __attribute__((ext_vector_type(4))) unsigned short us4;
typedef __attribute__((ext_vector_type(4))) float f32x4;

__device__ __forceinline__ float bf2f(unsigned short u) {
  union { unsigned int i; float f; } v; v.i = ((unsigned int)u) << 16; return v.f;
}
__device__ __forceinline__ unsigned short f2bf(float f) {
  union { float f; unsigned int i; } v; v.f = f;
  unsigned int u = v.i;
  u += 0x7FFFu + ((u >> 16) & 1u);
  return (unsigned short)(u >> 16);
}

__global__ void zero_f(float* p, int n) {
  int i = blockIdx.x * blockDim.x + threadIdx.x;
  if (i < n) p[i] = 0.f;
}

__global__ void zero_int(int* p, int n) {
  int stride = gridDim.x * blockDim.x;
  for (int i = blockIdx.x * blockDim.x + threadIdx.x; i < n; i += stride) p[i] = 0;
}

__global__ void encode_kernel(const int* __restrict__ x, const float* __restrict__ pe,
                              const float* __restrict__ ce, const float* __restrict__ le,
                              float* __restrict__ h, int n) {
  int total = n * HD;
  int stride = gridDim.x * blockDim.x;
  for (int idx = blockIdx.x * blockDim.x + threadIdx.x; idx < total; idx += stride) {
    int node = idx >> 7, c = idx & (HD - 1);
    int lv = x[node * 3 + 0]; lv = lv < 0 ? 0 : (lv > 999 ? 999 : lv);
    int ct = x[node * 3 + 1]; ct = ct < 0 ? 0 : (ct > 4 ? 4 : ct);
    int th = x[node * 3 + 2]; th = th < 0 ? 0 : (th > 4999 ? 4999 : th);
    h[idx] = ce[ct * HD + c] + le[lv * HD + c] + pe[th * HD + c];
  }
}

// split 7 [128][128] f32 weight mats into bf16 hi/lo, transposed [c][k], pre-swizzled
__global__ void prep_w(const float* __restrict__ cW1, const float* __restrict__ cW2,
                       const float* __restrict__ gW1,
                       unsigned short* __restrict__ whi, unsigned short* __restrict__ wlo) {
  int m = blockIdx.x;
  const float* W = (m < 3) ? cW1 + (size_t)m * HD * HD
                 : (m < 6) ? cW2 + (size_t)(m - 3) * HD * HD : gW1;
  unsigned short* oh = whi + (size_t)m * HD * HD;
  unsigned short* ol = wlo + (size_t)m * HD * HD;
  for (int i = threadIdx.x; i < HD * HD; i += 256) {
    int k = i >> 7, c = i & (HD - 1);
    float f = W[i];
    unsigned short hh = f2bf(f);
    unsigned short ll = f2bf(f - bf2f(hh));
    int g = k >> 3;
    int d = c * HD + (((g ^ (c & 7)) << 3) | (k & 7));
    oh[d] = hh;
    ol[d] = ll;
  }
}

// ---------------- CSR build ----------------------------------------------------

__global__ void hist_kernel(const int* __restrict__ ei, int* deg, int E) {
  int stride = gridDim.x * blockDim.x;
  for (int e = blockIdx.x * blockDim.x + threadIdx.x; e < E; e += stride)
    atomicAdd(&deg[ei[E + e]], 1);
}

#define SCAN_BS 1024
__global__ void scan1_kernel(const int* __restrict__ deg, int* __restrict__ off,
                             int* __restrict__ bsum, int n) {
  __shared__ int sh[256];
  int b = blockIdx.x, t = threadIdx.x;
  int base = b * SCAN_BS + t * 4;
  int v[4];
#pragma unroll
  for (int j = 0; j < 4; j++) v[j] = (base + j < n) ? deg[base + j] : 0;
  int s = v[0] + v[1] + v[2] + v[3];
  sh[t] = s;
  __syncthreads();
  for (int o = 1; o < 256; o <<= 1) {
    int x = (t >= o) ? sh[t - o] : 0;
    __syncthreads();
    sh[t] += x;
    __syncthreads();
  }
  int excl = sh[t] - s;
  if (t == 255) bsum[b] = sh[255];
  int run = excl;
#pragma unroll
  for (int j = 0; j < 4; j++) {
    if (base + j < n) off[base + j] = run;
    run += v[j];
  }
}

__global__ void scan2_kernel(int* bsum, int nb) {
  __shared__ int sh[128];
  int t = threadIdx.x;
  int v = (t < nb) ? bsum[t] : 0;
  sh[t] = v;
  __syncthreads();
  for (int o = 1; o < 128; o <<= 1) {
    int x = (t >= o) ? sh[t - o] : 0;
    __syncthreads();
    sh[t] += x;
    __syncthreads();
  }
  if (t < nb) bsum[t] = sh[t] - v;
}

__global__ void scan3_kernel(int* off, const int* __restrict__ bsum, int n, int E) {
  int idx = blockIdx.x * blockDim.x + threadIdx.x;
  int stride = gridDim.x * blockDim.x;
  for (int i = idx; i < n; i += stride) off[i] += bsum[i >> 10];
  if (idx == 0) off[n] = E;
}

__global__ void copy_int(const int* __restrict__ a, int* b, int n) {
  int stride = gridDim.x * blockDim.x;
  for (int i = blockIdx.x * blockDim.x + threadIdx.x; i < n; i += stride) b[i] = a[i];
}

// windowed fill: pass p (blockIdx.y) handles dst in [p<<14, (p+1)<<14) so csr_src
// writes + cursor atomics stay in an L2-resident window (kills 16x write amplification)
__global__ void fill_kernel(const int* __restrict__ ei, int* cursor, int* csr_src, int E) {
  int pass = blockIdx.y;
  int stride = gridDim.x * blockDim.x;
  for (int e = blockIdx.x * blockDim.x + threadIdx.x; e < E; e += stride) {
    int d = ei[E + e];
    if ((d >> 14) == pass) {
      int pos = atomicAdd(&cursor[d], 1);
      csr_src[pos] = ei[e];
    }
  }
}

// out[i] = f(h[i]) + sum f(h[src]); f = identity or relu(a*x+b); f32; 4-edge unroll
template<bool BN>
__global__ void gather_kernel(const float* __restrict__ h, const int* __restrict__ off,
                              const int* __restrict__ src, const float* __restrict__ ab,
                              float* __restrict__ out, int N) {
  int gid = (blockIdx.x * blockDim.x + threadIdx.x) >> 5;
  int lane = threadIdx.x & 31;
  int ng = (gridDim.x * blockDim.x) >> 5;
  float4 a4, b4;
  if (BN) {
    a4 = *(const float4*)(ab + lane * 4);
    b4 = *(const float4*)(ab + HD + lane * 4);
  }
#define APPLY_BN(v) if (BN) { \
    v.x = fmaxf(v.x * a4.x + b4.x, 0.f); \
    v.y = fmaxf(v.y * a4.y + b4.y, 0.f); \
    v.z = fmaxf(v.z * a4.z + b4.z, 0.f); \
    v.w = fmaxf(v.w * a4.w + b4.w, 0.f); }
  for (int i = gid; i < N; i += ng) {
    int s0 = off[i], s1 = off[i + 1];
    float4 acc0 = *(const float4*)(h + (size_t)i * HD + lane * 4);
    APPLY_BN(acc0);
    float4 acc1 = {0.f, 0.f, 0.f, 0.f};
    float4 acc2 = {0.f, 0.f, 0.f, 0.f};
    float4 acc3 = {0.f, 0.f, 0.f, 0.f};
    int e = s0;
    for (; e + 4 <= s1; e += 4) {
      int i0 = src[e], i1 = src[e + 1], i2 = src[e + 2], i3 = src[e + 3];
      float4 v0 = *(const float4*)(h + (size_t)i0 * HD + lane * 4);
      float4 v1 = *(const float4*)(h + (size_t)i1 * HD + lane * 4);
      float4 v2 = *(const float4*)(h + (size_t)i2 * HD + lane * 4);
      float4 v3 = *(const float4*)(h + (size_t)i3 * HD + lane * 4);
      APPLY_BN(v0); APPLY_BN(v1); APPLY_BN(v2); APPLY_BN(v3);
      acc0.x += v0.x; acc0.y += v0.y; acc0.z += v0.z; acc0.w += v0.w;
      acc1.x += v1.x; acc1.y += v1.y; acc1.z += v1.z; acc1.w += v1.w;
      acc2.x += v2.x; acc2.y += v2.y; acc2.z += v2.z; acc2.w += v2.w;
      acc3.x += v3.x; acc3.y += v3.y; acc3.z += v3.z; acc3.w += v3.w;
    }
    for (; e < s1; e++) {
      int s = src[e];
      float4 v = *(const float4*)(h + (size_t)s * HD + lane * 4);
      APPLY_BN(v);
      acc0.x += v.x; acc0.y += v.y; acc0.z += v.z; acc0.w += v.w;
    }
    acc0.x += acc1.x + acc2.x + acc3.x;
    acc0.y += acc1.y + acc2.y + acc3.y;
    acc0.z += acc1.z + acc2.z + acc3.z;
    acc0.w += acc1.w + acc2.w + acc3.w;
    *(float4*)(out + (size_t)i * HD + lane * 4) = acc0;
  }
#undef APPLY_BN
}

// ---------------- split-bf16 MFMA GEMM -----------------------------------------
template<bool INBN, bool GATE, bool STATS>
__global__ __launch_bounds__(512, 1)
void gemm_split(const float* __restrict__ X, const unsigned short* __restrict__ Whi,
                const unsigned short* __restrict__ Wlo,
                const float* __restrict__ bias, const float* __restrict__ ab,
                const float* __restrict__ w2, float* __restrict__ outf,
                float* __restrict__ gate, float* __restrict__ stat, int Nn) {
  __shared__ unsigned short XsH[128 * HD];
  __shared__ unsigned short XsL[128 * HD];
  __shared__ unsigned short WsH[HD * HD];
  __shared__ unsigned short WsL[HD * HD];
  __shared__ float red[2 * HD];
  int t = threadIdx.x;
  long rowbase = (long)blockIdx.x * 128;

#pragma unroll
  for (int it = 0; it < 8; it++) {
    int i = (t + it * 512) * 4;
    int r = i >> 7, k = i & (HD - 1);
    long row = rowbase + r; if (row > Nn - 1) row = Nn - 1;
    float4 v = *(const float4*)(X + row * HD + k);
    float f[4] = {v.x, v.y, v.z, v.w};
    if (INBN) {
#pragma unroll
      for (int j = 0; j < 4; j++)
        f[j] = fmaxf(f[j] * ab[k + j] + ab[HD + k + j], 0.f);
    }
    us4 hi, lo;
#pragma unroll
    for (int j = 0; j < 4; j++) {
      unsigned short hh = f2bf(f[j]);
      hi[j] = hh;
      lo[j] = f2bf(f[j] - bf2f(hh));
    }
    int g = k >> 3;
    int off = r * HD + ((((g ^ (r & 7)) << 3)) | (k & 7));
    *(us4*)(XsH + off) = hi;
    *(us4*)(XsL + off) = lo;
  }
#pragma unroll
  for (int it = 0; it < 4; it++) {
    int i = (t + it * 512) * 8;
    *(us8*)(WsH + i) = *(const us8*)(Whi + i);
    *(us8*)(WsL + i) = *(const us8*)(Wlo + i);
  }
  if (STATS && t < 2 * HD) red[t] = 0.f;
  __syncthreads();

  int w = t >> 6, l = t & 63;
  int lr = l & 15, lg = l >> 4;

  f32x4 acc[8];
#pragma unroll
  for (int ct = 0; ct < 8; ct++) acc[ct] = (f32x4){0.f, 0.f, 0.f, 0.f};

  bf16x8 aH[4], aL[4];
  int arow = w * 16 + lr;
#pragma unroll
  for (int k4 = 0; k4 < 4; k4++) {
    int kg = k4 * 4 + lg;
    int off = arow * HD + (((kg ^ (arow & 7)) << 3));
    aH[k4] = *(bf16x8*)(XsH + off);
    aL[k4] = *(bf16x8*)(XsL + off);
  }
#pragma unroll
  for (int ct = 0; ct < 8; ct++) {
    int c = ct * 16 + lr;
#pragma unroll
    for (int k4 = 0; k4 < 4; k4++) {
      int kg = k4 * 4 + lg;
      int off = c * HD + (((kg ^ (c & 7)) << 3));
      bf16x8 bH = *(bf16x8*)(WsH + off);
      bf16x8 bL = *(bf16x8*)(WsL + off);
      acc[ct] = __builtin_amdgcn_mfma_f32_16x16x32_bf16(aH[k4], bH, acc[ct], 0, 0, 0);
      acc[ct] = __builtin_amdgcn_mfma_f32_16x16x32_bf16(aH[k4], bL, acc[ct], 0, 0, 0);
      acc[ct] = __builtin_amdgcn_mfma_f32_16x16x32_bf16(aL[k4], bH, acc[ct], 0, 0, 0);
    }
  }

  if (GATE) {
#pragma unroll
    for (int jj = 0; jj < 4; jj++) {
      float p = 0.f;
#pragma unroll
      for (int ct = 0; ct < 8; ct++) {
        float v = fmaxf(acc[ct][jj] + bias[ct * 16 + lr], 0.f);
        p += v * w2[ct * 16 + lr];
      }
      p += __shfl_xor(p, 1);
      p += __shfl_xor(p, 2);
      p += __shfl_xor(p, 4);
      p += __shfl_xor(p, 8);
      long row = rowbase + w * 16 + lg * 4 + jj;
      if (lr == 0 && row < Nn) gate[row] = p;
    }
  } else {
    float s[8], ss[8];
#pragma unroll
    for (int ct = 0; ct < 8; ct++) { s[ct] = 0.f; ss[ct] = 0.f; }
#pragma unroll
    for (int jj = 0; jj < 4; jj++) {
      long row = rowbase + w * 16 + lg * 4 + jj;
      bool ok = row < Nn;
#pragma unroll
      for (int ct = 0; ct < 8; ct++) {
        float v = acc[ct][jj] + bias[ct * 16 + lr];
        if (ok) {
          outf[row * HD + ct * 16 + lr] = v;
          if (STATS) { s[ct] += v; ss[ct] += v * v; }
        }
      }
    }
    if (STATS) {
#pragma unroll
      for (int ct = 0; ct < 8; ct++) {
        float sv = s[ct], sq = ss[ct];
        sv += __shfl_xor(sv, 16); sq += __shfl_xor(sq, 16);
        sv += __shfl_xor(sv, 32); sq += __shfl_xor(sq, 32);
        if (lg == 0) {
          atomicAdd(&red[ct * 16 + lr], sv);
          atomicAdd(&red[HD + ct * 16 + lr], sq);
        }
      }
      __syncthreads();
      float* st = stat + (blockIdx.x & 3) * 256;
      if (t < HD) {
        atomicAdd(&st[t], red[t]);
        atomicAdd(&st[HD + t], red[HD + t]);
      }
    }
  }
}

__global__ void finalize_kernel(const float* __restrict__ stat, const float* __restrict__ g,
                                const float* __restrict__ be, float* ab, float inv_n) {
  int c = threadIdx.x;
  float s = stat[c] + stat[256 + c] + stat[512 + c] + stat[768 + c];
  float sq = stat[HD + c] + stat[256 + HD + c] + stat[512 + HD + c] + stat[768 + HD + c];
  float mean = s * inv_n;
  float var = sq * inv_n - mean * mean;
  float inv = rsqrtf(var + 1e-5f);
  float a = inv * g[c];
  ab[c] = a;
  ab[HD + c] = be[c] - mean * a;
}

__global__ void finalize1_kernel(const float* __restrict__ stat, const float* __restrict__ g,
                                 const float* __restrict__ be, float* ab, float inv_n) {
  int c = threadIdx.x;
  float mean = stat[c] * inv_n;
  float var = stat[HD + c] * inv_n - mean * mean;
  float inv = rsqrtf(var + 1e-5f);
  float a = inv * g[c];
  ab[c] = a;
  ab[HD + c] = be[c] - mean * a;
}

__global__ void bound_kernel(const int* __restrict__ batch, int* gs, int N, int G) {
  int i = blockIdx.x * blockDim.x + threadIdx.x;
  if (i >= N) return;
  int b = batch[i];
  int prev = (i == 0) ? -1 : batch[i - 1];
  for (int g = prev + 1; g <= b; g++) gs[g] = i;
  if (i == N - 1)
    for (int g = b + 1; g <= G; g++) gs[g] = N;
}

// per-graph softmax pool with deferred BN; 4-row unroll on the weighted pass
__global__ void fused_pool(const float* __restrict__ h, const float* __restrict__ gate,
                           const int* __restrict__ gs, const float* __restrict__ ab,
                           float* __restrict__ pooled) {
  int g = blockIdx.x;
  int t = threadIdx.x;
  int s0 = gs[g], s1 = gs[g + 1];
  if (s0 >= s1) { pooled[(size_t)g * HD + t] = 0.f; return; }
  __shared__ float red[HD];
  float m = -INFINITY;
  for (int i = s0 + t; i < s1; i += HD) m = fmaxf(m, gate[i]);
  red[t] = m;
  __syncthreads();
  for (int o = 64; o > 0; o >>= 1) {
    if (t < o) red[t] = fmaxf(red[t], red[t + o]);
    __syncthreads();
  }
  m = red[0];
  __syncthreads();
  float s = 0.f;
  for (int i = s0 + t; i < s1; i += HD) s += expf(gate[i] - m);
  red[t] = s;
  __syncthreads();
  for (int o = 64; o > 0; o >>= 1) {
    if (t < o) red[t] += red[t + o];
    __syncthreads();
  }
  float inv = 1.f / red[0];
  float a = ab[t], b = ab[HD + t];
  float acc = 0.f;
  int i = s0;
  for (; i + 4 <= s1; i += 4) {
    float al0 = expf(gate[i] - m);
    float al1 = expf(gate[i + 1] - m);
    float al2 = expf(gate[i + 2] - m);
    float al3 = expf(gate[i + 3] - m);
    float v0 = fmaxf(h[(size_t)(i + 0) * HD + t] * a + b, 0.f);
    float v1 = fmaxf(h[(size_t)(i + 1) * HD + t] * a + b, 0.f);
    float v2 = fmaxf(h[(size_t)(i + 2) * HD + t] * a + b, 0.f);
    float v3 = fmaxf(h[(size_t)(i + 3) * HD + t] * a + b, 0.f);
    acc += al0 * v0 + al1 * v1 + al2 * v2 + al3 * v3;
  }
  for (; i < s1; i++) {
    float al = expf(gate[i] - m);
    float v = fmaxf(h[(size_t)i * HD + t] * a + b, 0.f);
    acc += al * v;
  }
  pooled[(size_t)g * HD + t] = acc * inv;
}

// f32 classifier GEMM: zc[G x 128] = pooled @ W + bias
__global__ __launch_bounds__(256, 4)
void gemm_f32(const float* __restrict__ X, const float* __restrict__ W,
              const float* __restrict__ bias, float* __restrict__ out, int Nn) {
  __shared__ float XsT[32][132];
  __shared__ float Ws[32][HD];
  int t = threadIdx.x;
  int r0 = (t >> 4) * 8;
  int c0 = (t & 15) * 8;
  long rowbase = (long)blockIdx.x * 128;

  float acc[8][8];
#pragma unroll
  for (int ci = 0; ci < 8; ci++) {
    float bv = bias[c0 + ci];
#pragma unroll
    for (int ri = 0; ri < 8; ri++) acc[ri][ci] = bv;
  }

  int sr = t >> 1;
  int hf = t & 1;
  long srow = rowbase + sr; if (srow > Nn - 1) srow = Nn - 1;
  const float* xrow = X + srow * HD;

  for (int k0 = 0; k0 < HD; k0 += 32) {
    __syncthreads();
#pragma unroll
    for (int j = 0; j < 4; j++) {
      int i = j * 1024 + t * 4;
      int kk = i >> 7, c = i & (HD - 1);
      *(float4*)&Ws[kk][c] = *(const float4*)&W[(size_t)(k0 + kk) * HD + c];
    }
#pragma unroll
    for (int j = 0; j < 4; j++) {
      int kc = k0 + hf * 16 + j * 4;
      float4 v = *(const float4*)&xrow[kc];
      int kl = hf * 16 + j * 4;
      XsT[kl + 0][sr] = v.x;
      XsT[kl + 1][sr] = v.y;
      XsT[kl + 2][sr] = v.z;
      XsT[kl + 3][sr] = v.w;
    }
    __syncthreads();
#pragma unroll 8
    for (int kk = 0; kk < 32; kk++) {
      float4 a0 = *(float4*)&XsT[kk][r0];
      float4 a1 = *(float4*)&XsT[kk][r0 + 4];
      float4 b0 = *(float4*)&Ws[kk][c0];
      float4 b1 = *(float4*)&Ws[kk][c0 + 4];
      float ar[8] = {a0.x, a0.y, a0.z, a0.w, a1.x, a1.y, a1.z, a1.w};
      float bc[8] = {b0.x, b0.y, b0.z, b0.w, b1.x, b1.y, b1.z, b1.w};
#pragma unroll
      for (int ri = 0; ri < 8; ri++)
#pragma unroll
        for (int ci = 0; ci < 8; ci++) acc[ri][ci] += ar[ri] * bc[ci];
    }
  }

#pragma unroll
  for (int ri = 0; ri < 8; ri++) {
    long row = rowbase + r0 + ri;
    if (row < Nn) {
      float4 o0 = {acc[ri][0], acc[ri][1], acc[ri][2], acc[ri][3]};
      float4 o1 = {acc[ri][4], acc[ri][5], acc[ri][6], acc[ri][7]};
      *(float4*)&out[row * HD + c0] = o0;
      *(float4*)&out[row * HD + c0 + 4] = o1;
    }
  }
}

__global__ void stats_f32(const float* __restrict__ z, float* stat, int n) {
  int c = threadIdx.x & (HD - 1);
  int rg = threadIdx.x >> 7;
  float s = 0.f, ss = 0.f;
  for (int r = blockIdx.x * 2 + rg; r < n; r += gridDim.x * 2) {
    float v = z[(size_t)r * HD + c];
    s += v; ss += v * v;
  }
  __shared__ float S[2][HD], SS[2][HD];
  S[rg][c] = s; SS[rg][c] = ss;
  __syncthreads();
  if (threadIdx.x < HD) {
    atomicAdd(&stat[c], S[0][c] + S[1][c]);
    atomicAdd(&stat[HD + c], SS[0][c] + SS[1][c]);
  }
}

__global__ void cls_out_kernel(const float* __restrict__ zc, const float* __restrict__ ab,
                               const float* __restrict__ W2, const float* __restrict__ b2,
                               float* out, int G) {
  int row = blockIdx.x;
  int t = threadIdx.x;
  float v0 = fmaxf(zc[(size_t)row * HD + t] * ab[t] + ab[HD + t], 0.f);
  float v1 = fmaxf(zc[(size_t)row * HD + 64 + t] * ab[64 + t] + ab[HD + 64 + t], 0.f);
  for (int o = 0; o < 10; o++) {
    float p = v0 * W2[t * 10 + o] + v1 * W2[(64 + t) * 10 + o];
#pragma unroll
    for (int s = 32; s > 0; s >>= 1) p += __shfl_down(p, s);
    if (t == 0) out[row * 10 + o] = p + b2[o];
  }
}

extern "C" void kernel_launch(void* const* d_in, const int* in_sizes, int n_in,
                              void* d_out, int out_size, void* d_ws, size_t ws_size,
                              hipStream_t stream) {
  const int* x     = (const int*)d_in[0];
  const int* ei    = (const int*)d_in[1];
  const int* batch = (const int*)d_in[2];
  const float* pe  = (const float*)d_in[4];
  const float* ce  = (const float*)d_in[5];
  const float* le  = (const float*)d_in[6];
  const float* cW1 = (const float*)d_in[7];
  const float* cb1 = (const float*)d_in[8];
  const float* cg1 = (const float*)d_in[9];
  const float* cbe1= (const float*)d_in[10];
  const float* cW2 = (const float*)d_in[11];
  const float* cb2 = (const float*)d_in[12];
  const float* ngm = (const float*)d_in[13];
  const float* nbe = (const float*)d_in[14];
  const float* gW1 = (const float*)d_in[15];
  const float* gb1 = (const float*)d_in[16];
  const float* gW2 = (const float*)d_in[17];
  const float* clW1= (const float*)d_in[19];
  const float* clb1= (const float*)d_in[20];
  const float* clg = (const float*)d_in[21];
  const float* clbe= (const float*)d_in[22];
  const float* clW2= (const float*)d_in[23];
  const float* clb2= (const float*)d_in[24];

  int N = in_sizes[2];
  int E = in_sizes[1] / 2;
  int G = out_size / 10;

  float* buf0   = (float*)d_ws;              // h (f32)
  float* buf1   = buf0 + (size_t)N * HD;     // h+agg / z (f32)
  float* pooled = buf1 + (size_t)N * HD;     // G x 128
  float* gate   = pooled + (size_t)G * HD;   // N
  float* zc     = gate + N;                  // G x 128
  float* stats  = zc + (size_t)G * HD;       // 7 x 1024
  float* ab     = stats + 7 * 1024;          // 7 x 256
  unsigned short* whi = (unsigned short*)(ab + 7 * 256);  // 7 x 128 x 128 bf16
  unsigned short* wlo = whi + 7 * HD * HD;
  int* csr_off  = (int*)(wlo + 7 * HD * HD); // N+1
  int* cursor   = csr_off + (N + 1);         // N
  int* bsum     = cursor + N;                // 128
  int* gs       = bsum + 128;                // G+1
  int* csr_src  = gs + (G + 1);              // E

  float* out = (float*)d_out;
  int gemmBlocks = (N + 127) / 128;

  zero_f<<<28, 256, 0, stream>>>(stats, 7 * 1024);
  encode_kernel<<<2048, 256, 0, stream>>>(x, pe, ce, le, buf0, N);
  prep_w<<<7, 256, 0, stream>>>(cW1, cW2, gW1, whi, wlo);

  // CSR build (reused by all 3 layers)
  int nb = (N + SCAN_BS - 1) / SCAN_BS;
  zero_int<<<256, 256, 0, stream>>>(cursor, N);
  hist_kernel<<<2048, 256, 0, stream>>>(ei, cursor, E);
  scan1_kernel<<<nb, 256, 0, stream>>>(cursor, csr_off, bsum, N);
  scan2_kernel<<<1, 128, 0, stream>>>(bsum, nb);
  scan3_kernel<<<256, 256, 0, stream>>>(csr_off, bsum, N, E);
  copy_int<<<256, 256, 0, stream>>>(csr_off, cursor, N);
  int npass = (N + (1 << 14) - 1) >> 14;
  fill_kernel<<<dim3(256, npass), 256, 0, stream>>>(ei, cursor, csr_src, E);
  bound_kernel<<<(N + 255) / 256, 256, 0, stream>>>(batch, gs, N, G);

  for (int l = 0; l < 3; l++) {
    float* abPrev = ab + (l - 1) * 512 + 256;
    if (l == 0)
      gather_kernel<false><<<2048, 256, 0, stream>>>(buf0, csr_off, csr_src, nullptr, buf1, N);
    else
      gather_kernel<true><<<2048, 256, 0, stream>>>(buf0, csr_off, csr_src, abPrev, buf1, N);
    gemm_split<false, false, true><<<gemmBlocks, 512, 0, stream>>>(
        buf1, whi + (size_t)l * HD * HD, wlo + (size_t)l * HD * HD,
        cb1 + l * HD, nullptr, nullptr, buf1, nullptr, stats + l * 2048, N);
    finalize_kernel<<<1, 128, 0, stream>>>(stats + l * 2048, cg1 + l * HD, cbe1 + l * HD,
                                           ab + l * 512, 1.f / N);
    gemm_split<true, false, true><<<gemmBlocks, 512, 0, stream>>>(
        buf1, whi + (size_t)(3 + l) * HD * HD, wlo + (size_t)(3 + l) * HD * HD,
        cb2 + l * HD, ab + l * 512, nullptr, buf0, nullptr, stats + l * 2048 + 1024, N);
    finalize_kernel<<<1, 128, 0, stream>>>(stats + l * 2048 + 1024, ngm + l * HD, nbe + l * HD,
                                           ab + l * 512 + 256, 1.f / N);
  }

  const float* abFin = ab + 2 * 512 + 256;
  gemm_split<true, true, false><<<gemmBlocks, 512, 0, stream>>>(
      buf0, whi + (size_t)6 * HD * HD, wlo + (size_t)6 * HD * HD,
      gb1, abFin, gW2, nullptr, gate, nullptr, N);
  fused_pool<<<G, HD, 0, stream>>>(buf0, gate, gs, abFin, pooled);

  // classifier tail in f32
  gemm_f32<<<(G + 127) / 128, 256, 0, stream>>>(pooled, clW1, clb1, zc, G);
  stats_f32<<<64, 256, 0, stream>>>(zc, stats + 6 * 1024, G);
  finalize1_kernel<<<1, 128, 0, stream>>>(stats + 6 * 1024, clg, clbe, ab + 6 * 256, 1.f / G);
  cls_out_kernel<<<G, 64, 0, stream>>>(zc, ab + 6 * 256, clW2, clb2, out, G);
}

// Round 8
// 935.583 us; speedup vs baseline: 10.3678x; 1.1244x over previous
//
#include <hip/hip_runtime.h>
#include <math.h>

#define HD 128

typedef __attribute__((ext_vector_type(8))) short bf16x8;
typedef __attribute__((ext_vector_type(8))) unsigned short us8;
typedef __attribute__((ext_vector_type(4))) unsigned short us4;
typedef __attribute__((ext_vector_type(4))) float f32x4;

__device__ __forceinline__ float bf2f(unsigned short u) {
  union { unsigned int i; float f; } v; v.i = ((unsigned int)u) << 16; return v.f;
}
__device__ __forceinline__ unsigned short f2bf(float f) {
  union { float f; unsigned int i; } v; v.f = f;
  unsigned int u = v.i;
  u += 0x7FFFu + ((u >> 16) & 1u);
  return (unsigned short)(u >> 16);
}

__global__ void zero_f(float* p, int n) {
  int i = blockIdx.x * blockDim.x + threadIdx.x;
  if (i < n) p[i] = 0.f;
}

__global__ void zero_int(int* p, int n) {
  int stride = gridDim.x * blockDim.x;
  for (int i = blockIdx.x * blockDim.x + threadIdx.x; i < n; i += stride) p[i] = 0;
}

__global__ void encode_kernel(const int* __restrict__ x, const float* __restrict__ pe,
                              const float* __restrict__ ce, const float* __restrict__ le,
                              float* __restrict__ h, int n) {
  int total = n * HD;
  int stride = gridDim.x * blockDim.x;
  for (int idx = blockIdx.x * blockDim.x + threadIdx.x; idx < total; idx += stride) {
    int node = idx >> 7, c = idx & (HD - 1);
    int lv = x[node * 3 + 0]; lv = lv < 0 ? 0 : (lv > 999 ? 999 : lv);
    int ct = x[node * 3 + 1]; ct = ct < 0 ? 0 : (ct > 4 ? 4 : ct);
    int th = x[node * 3 + 2]; th = th < 0 ? 0 : (th > 4999 ? 4999 : th);
    h[idx] = ce[ct * HD + c] + le[lv * HD + c] + pe[th * HD + c];
  }
}

// split 7 [128][128] f32 weight mats into bf16 hi/lo in WAVE-TILED fragment layout:
// out[((ct*4+k4)*64 + lane)*8 + j] = W[k][c], c = ct*16+(lane&15), k = (k4*4+(lane>>4))*8+j
// -> B-fragment load in GEMM is wave-uniform base + lane*16B (fully coalesced, L1-resident)
__global__ void prep_w(const float* __restrict__ cW1, const float* __restrict__ cW2,
                       const float* __restrict__ gW1,
                       unsigned short* __restrict__ whi, unsigned short* __restrict__ wlo) {
  int m = blockIdx.x;
  const float* W = (m < 3) ? cW1 + (size_t)m * HD * HD
                 : (m < 6) ? cW2 + (size_t)(m - 3) * HD * HD : gW1;
  unsigned short* oh = whi + (size_t)m * HD * HD;
  unsigned short* ol = wlo + (size_t)m * HD * HD;
  for (int i = threadIdx.x; i < HD * HD; i += 256) {
    int j = i & 7;
    int l = (i >> 3) & 63;
    int p = i >> 9;            // ct*4 + k4
    int ct = p >> 2, k4 = p & 3;
    int c = ct * 16 + (l & 15);
    int k = (k4 * 4 + (l >> 4)) * 8 + j;
    float f = W[k * HD + c];
    unsigned short hh = f2bf(f);
    oh[i] = hh;
    ol[i] = f2bf(f - bf2f(hh));
  }
}

// ---------------- CSR build ----------------------------------------------------
// XCD-owned windows: pass p = blockIdx.x & 7 handles dst in [p*Wwin, (p+1)*Wwin).
// blockIdx->XCD is round-robin on MI355X, so all writes completing a given 64B
// line of csr_src/deg come from ONE XCD's L2 -> full-line writebacks (kills the
// 16x sub-line RMW amplification seen in R7). Perf-only heuristic.

__global__ void hist_kernel(const int* __restrict__ ei, int* deg, int E, int Wwin) {
  int pass = blockIdx.x & 7;
  int b = blockIdx.x >> 3;
  int tstride = (gridDim.x >> 3) * blockDim.x;
  for (int e = b * blockDim.x + threadIdx.x; e < E; e += tstride) {
    int d = ei[E + e];
    if (d / Wwin == pass) atomicAdd(&deg[d], 1);
  }
}

#define SCAN_BS 1024
__global__ void scan1_kernel(const int* __restrict__ deg, int* __restrict__ off,
                             int* __restrict__ bsum, int n) {
  __shared__ int sh[256];
  int b = blockIdx.x, t = threadIdx.x;
  int base = b * SCAN_BS + t * 4;
  int v[4];
#pragma unroll
  for (int j = 0; j < 4; j++) v[j] = (base + j < n) ? deg[base + j] : 0;
  int s = v[0] + v[1] + v[2] + v[3];
  sh[t] = s;
  __syncthreads();
  for (int o = 1; o < 256; o <<= 1) {
    int x = (t >= o) ? sh[t - o] : 0;
    __syncthreads();
    sh[t] += x;
    __syncthreads();
  }
  int excl = sh[t] - s;
  if (t == 255) bsum[b] = sh[255];
  int run = excl;
#pragma unroll
  for (int j = 0; j < 4; j++) {
    if (base + j < n) off[base + j] = run;
    run += v[j];
  }
}

__global__ void scan2_kernel(int* bsum, int nb) {
  __shared__ int sh[128];
  int t = threadIdx.x;
  int v = (t < nb) ? bsum[t] : 0;
  sh[t] = v;
  __syncthreads();
  for (int o = 1; o < 128; o <<= 1) {
    int x = (t >= o) ? sh[t - o] : 0;
    __syncthreads();
    sh[t] += x;
    __syncthreads();
  }
  if (t < nb) bsum[t] = sh[t] - v;
}

// finalize csr_off and initialize cursor in one pass
__global__ void scan3_kernel(int* off, int* cursor, const int* __restrict__ bsum,
                             int n, int E) {
  int idx = blockIdx.x * blockDim.x + threadIdx.x;
  int stride = gridDim.x * blockDim.x;
  for (int i = idx; i < n; i += stride) {
    int v = off[i] + bsum[i >> 10];
    off[i] = v;
    cursor[i] = v;
  }
  if (idx == 0) off[n] = E;
}

__global__ void fill_kernel(const int* __restrict__ ei, int* cursor, int* csr_src,
                            int E, int Wwin) {
  int pass = blockIdx.x & 7;
  int b = blockIdx.x >> 3;
  int tstride = (gridDim.x >> 3) * blockDim.x;
  for (int e = b * blockDim.x + threadIdx.x; e < E; e += tstride) {
    int d = ei[E + e];
    if (d / Wwin == pass) {
      int pos = atomicAdd(&cursor[d], 1);
      csr_src[pos] = ei[e];
    }
  }
}

// out[i] = f(h[i]) + sum f(h[src]); f = identity or relu(a*x+b); f32; 4-edge unroll
template<bool BN>
__global__ void gather_kernel(const float* __restrict__ h, const int* __restrict__ off,
                              const int* __restrict__ src, const float* __restrict__ ab,
                              float* __restrict__ out, int N) {
  int gid = (blockIdx.x * blockDim.x + threadIdx.x) >> 5;
  int lane = threadIdx.x & 31;
  int ng = (gridDim.x * blockDim.x) >> 5;
  float4 a4, b4;
  if (BN) {
    a4 = *(const float4*)(ab + lane * 4);
    b4 = *(const float4*)(ab + HD + lane * 4);
  }
#define APPLY_BN(v) if (BN) { \
    v.x = fmaxf(v.x * a4.x + b4.x, 0.f); \
    v.y = fmaxf(v.y * a4.y + b4.y, 0.f); \
    v.z = fmaxf(v.z * a4.z + b4.z, 0.f); \
    v.w = fmaxf(v.w * a4.w + b4.w, 0.f); }
  for (int i = gid; i < N; i += ng) {
    int s0 = off[i], s1 = off[i + 1];
    float4 acc0 = *(const float4*)(h + (size_t)i * HD + lane * 4);
    APPLY_BN(acc0);
    float4 acc1 = {0.f, 0.f, 0.f, 0.f};
    float4 acc2 = {0.f, 0.f, 0.f, 0.f};
    float4 acc3 = {0.f, 0.f, 0.f, 0.f};
    int e = s0;
    for (; e + 4 <= s1; e += 4) {
      int i0 = src[e], i1 = src[e + 1], i2 = src[e + 2], i3 = src[e + 3];
      float4 v0 = *(const float4*)(h + (size_t)i0 * HD + lane * 4);
      float4 v1 = *(const float4*)(h + (size_t)i1 * HD + lane * 4);
      float4 v2 = *(const float4*)(h + (size_t)i2 * HD + lane * 4);
      float4 v3 = *(const float4*)(h + (size_t)i3 * HD + lane * 4);
      APPLY_BN(v0); APPLY_BN(v1); APPLY_BN(v2); APPLY_BN(v3);
      acc0.x += v0.x; acc0.y += v0.y; acc0.z += v0.z; acc0.w += v0.w;
      acc1.x += v1.x; acc1.y += v1.y; acc1.z += v1.z; acc1.w += v1.w;
      acc2.x += v2.x; acc2.y += v2.y; acc2.z += v2.z; acc2.w += v2.w;
      acc3.x += v3.x; acc3.y += v3.y; acc3.z += v3.z; acc3.w += v3.w;
    }
    for (; e < s1; e++) {
      int s = src[e];
      float4 v = *(const float4*)(h + (size_t)s * HD + lane * 4);
      APPLY_BN(v);
      acc0.x += v.x; acc0.y += v.y; acc0.z += v.z; acc0.w += v.w;
    }
    acc0.x += acc1.x + acc2.x + acc3.x;
    acc0.y += acc1.y + acc2.y + acc3.y;
    acc0.z += acc1.z + acc2.z + acc3.z;
    acc0.w += acc1.w + acc2.w + acc3.w;
    *(float4*)(out + (size_t)i * HD + lane * 4) = acc0;
  }
#undef APPLY_BN
}

// ---------------- split-bf16 MFMA GEMM -----------------------------------------
// A*B ~= Ah*Bh + Ah*Bl + Al*Bh; X staged hi/lo in LDS (65 KB -> 2 blocks/CU);
// B fragments read from global wave-tiled table (L1-resident, coalesced 16B/lane).
template<bool INBN, bool GATE, bool STATS>
__global__ __launch_bounds__(512, 4)
void gemm_split(const float* __restrict__ X, const unsigned short* __restrict__ Whi,
                const unsigned short* __restrict__ Wlo,
                const float* __restrict__ bias, const float* __restrict__ ab,
                const float* __restrict__ w2, float* __restrict__ outf,
                float* __restrict__ gate, float* __restrict__ stat, int Nn) {
  __shared__ unsigned short XsH[128 * HD];
  __shared__ unsigned short XsL[128 * HD];
  __shared__ float red[2 * HD];
  int t = threadIdx.x;
  long rowbase = (long)blockIdx.x * 128;

#pragma unroll
  for (int it = 0; it < 8; it++) {
    int i = (t + it * 512) * 4;
    int r = i >> 7, k = i & (HD - 1);
    long row = rowbase + r; if (row > Nn - 1) row = Nn - 1;
    float4 v = *(const float4*)(X + row * HD + k);
    float f[4] = {v.x, v.y, v.z, v.w};
    if (INBN) {
#pragma unroll
      for (int j = 0; j < 4; j++)
        f[j] = fmaxf(f[j] * ab[k + j] + ab[HD + k + j], 0.f);
    }
    us4 hi, lo;
#pragma unroll
    for (int j = 0; j < 4; j++) {
      unsigned short hh = f2bf(f[j]);
      hi[j] = hh;
      lo[j] = f2bf(f[j] - bf2f(hh));
    }
    int g = k >> 3;
    int off = r * HD + ((((g ^ (r & 7)) << 3)) | (k & 7));
    *(us4*)(XsH + off) = hi;
    *(us4*)(XsL + off) = lo;
  }
  if (STATS && t < 2 * HD) red[t] = 0.f;
  __syncthreads();

  int w = t >> 6, l = t & 63;
  int lr = l & 15, lg = l >> 4;

  f32x4 acc[8];
#pragma unroll
  for (int ct = 0; ct < 8; ct++) acc[ct] = (f32x4){0.f, 0.f, 0.f, 0.f};

  bf16x8 aH[4], aL[4];
  int arow = w * 16 + lr;
#pragma unroll
  for (int k4 = 0; k4 < 4; k4++) {
    int kg = k4 * 4 + lg;
    int off = arow * HD + (((kg ^ (arow & 7)) << 3));
    aH[k4] = *(bf16x8*)(XsH + off);
    aL[k4] = *(bf16x8*)(XsL + off);
  }
#pragma unroll
  for (int ct = 0; ct < 8; ct++) {
#pragma unroll
    for (int k4 = 0; k4 < 4; k4++) {
      int bo = (((ct << 2) + k4) * 64 + l) * 8;
      bf16x8 bH = *(const bf16x8*)(Whi + bo);
      bf16x8 bL = *(const bf16x8*)(Wlo + bo);
      acc[ct] = __builtin_amdgcn_mfma_f32_16x16x32_bf16(aH[k4], bH, acc[ct], 0, 0, 0);
      acc[ct] = __builtin_amdgcn_mfma_f32_16x16x32_bf16(aH[k4], bL, acc[ct], 0, 0, 0);
      acc[ct] = __builtin_amdgcn_mfma_f32_16x16x32_bf16(aL[k4], bH, acc[ct], 0, 0, 0);
    }
  }

  // D layout: row_in_blk = w*16 + lg*4 + jj, col = ct*16 + lr
  if (GATE) {
#pragma unroll
    for (int jj = 0; jj < 4; jj++) {
      float p = 0.f;
#pragma unroll
      for (int ct = 0; ct < 8; ct++) {
        float v = fmaxf(acc[ct][jj] + bias[ct * 16 + lr], 0.f);
        p += v * w2[ct * 16 + lr];
      }
      p += __shfl_xor(p, 1);
      p += __shfl_xor(p, 2);
      p += __shfl_xor(p, 4);
      p += __shfl_xor(p, 8);
      long row = rowbase + w * 16 + lg * 4 + jj;
      if (lr == 0 && row < Nn) gate[row] = p;
    }
  } else {
    float s[8], ss[8];
#pragma unroll
    for (int ct = 0; ct < 8; ct++) { s[ct] = 0.f; ss[ct] = 0.f; }
#pragma unroll
    for (int jj = 0; jj < 4; jj++) {
      long row = rowbase + w * 16 + lg * 4 + jj;
      bool ok = row < Nn;
#pragma unroll
      for (int ct = 0; ct < 8; ct++) {
        float v = acc[ct][jj] + bias[ct * 16 + lr];
        if (ok) {
          outf[row * HD + ct * 16 + lr] = v;
          if (STATS) { s[ct] += v; ss[ct] += v * v; }
        }
      }
    }
    if (STATS) {
#pragma unroll
      for (int ct = 0; ct < 8; ct++) {
        float sv = s[ct], sq = ss[ct];
        sv += __shfl_xor(sv, 16); sq += __shfl_xor(sq, 16);
        sv += __shfl_xor(sv, 32); sq += __shfl_xor(sq, 32);
        if (lg == 0) {
          atomicAdd(&red[ct * 16 + lr], sv);
          atomicAdd(&red[HD + ct * 16 + lr], sq);
        }
      }
      __syncthreads();
      float* st = stat + (blockIdx.x & 3) * 256;
      if (t < HD) {
        atomicAdd(&st[t], red[t]);
        atomicAdd(&st[HD + t], red[HD + t]);
      }
    }
  }
}

__global__ void finalize_kernel(const float* __restrict__ stat, const float* __restrict__ g,
                                const float* __restrict__ be, float* ab, float inv_n) {
  int c = threadIdx.x;
  float s = stat[c] + stat[256 + c] + stat[512 + c] + stat[768 + c];
  float sq = stat[HD + c] + stat[256 + HD + c] + stat[512 + HD + c] + stat[768 + HD + c];
  float mean = s * inv_n;
  float var = sq * inv_n - mean * mean;
  float inv = rsqrtf(var + 1e-5f);
  float a = inv * g[c];
  ab[c] = a;
  ab[HD + c] = be[c] - mean * a;
}

__global__ void finalize1_kernel(const float* __restrict__ stat, const float* __restrict__ g,
                                 const float* __restrict__ be, float* ab, float inv_n) {
  int c = threadIdx.x;
  float mean = stat[c] * inv_n;
  float var = stat[HD + c] * inv_n - mean * mean;
  float inv = rsqrtf(var + 1e-5f);
  float a = inv * g[c];
  ab[c] = a;
  ab[HD + c] = be[c] - mean * a;
}

__global__ void bound_kernel(const int* __restrict__ batch, int* gs, int N, int G) {
  int i = blockIdx.x * blockDim.x + threadIdx.x;
  if (i >= N) return;
  int b = batch[i];
  int prev = (i == 0) ? -1 : batch[i - 1];
  for (int g = prev + 1; g <= b; g++) gs[g] = i;
  if (i == N - 1)
    for (int g = b + 1; g <= G; g++) gs[g] = N;
}

// per-graph softmax pool with deferred BN; 4-row unroll on the weighted pass
__global__ void fused_pool(const float* __restrict__ h, const float* __restrict__ gate,
                           const int* __restrict__ gs, const float* __restrict__ ab,
                           float* __restrict__ pooled) {
  int g = blockIdx.x;
  int t = threadIdx.x;
  int s0 = gs[g], s1 = gs[g + 1];
  if (s0 >= s1) { pooled[(size_t)g * HD + t] = 0.f; return; }
  __shared__ float red[HD];
  float m = -INFINITY;
  for (int i = s0 + t; i < s1; i += HD) m = fmaxf(m, gate[i]);
  red[t] = m;
  __syncthreads();
  for (int o = 64; o > 0; o >>= 1) {
    if (t < o) red[t] = fmaxf(red[t], red[t + o]);
    __syncthreads();
  }
  m = red[0];
  __syncthreads();
  float s = 0.f;
  for (int i = s0 + t; i < s1; i += HD) s += expf(gate[i] - m);
  red[t] = s;
  __syncthreads();
  for (int o = 64; o > 0; o >>= 1) {
    if (t < o) red[t] += red[t + o];
    __syncthreads();
  }
  float inv = 1.f / red[0];
  float a = ab[t], b = ab[HD + t];
  float acc = 0.f;
  int i = s0;
  for (; i + 4 <= s1; i += 4) {
    float al0 = expf(gate[i] - m);
    float al1 = expf(gate[i + 1] - m);
    float al2 = expf(gate[i + 2] - m);
    float al3 = expf(gate[i + 3] - m);
    float v0 = fmaxf(h[(size_t)(i + 0) * HD + t] * a + b, 0.f);
    float v1 = fmaxf(h[(size_t)(i + 1) * HD + t] * a + b, 0.f);
    float v2 = fmaxf(h[(size_t)(i + 2) * HD + t] * a + b, 0.f);
    float v3 = fmaxf(h[(size_t)(i + 3) * HD + t] * a + b, 0.f);
    acc += al0 * v0 + al1 * v1 + al2 * v2 + al3 * v3;
  }
  for (; i < s1; i++) {
    float al = expf(gate[i] - m);
    float v = fmaxf(h[(size_t)i * HD + t] * a + b, 0.f);
    acc += al * v;
  }
  pooled[(size_t)g * HD + t] = acc * inv;
}

// f32 classifier GEMM: zc[G x 128] = pooled @ W + bias
__global__ __launch_bounds__(256, 4)
void gemm_f32(const float* __restrict__ X, const float* __restrict__ W,
              const float* __restrict__ bias, float* __restrict__ out, int Nn) {
  __shared__ float XsT[32][132];
  __shared__ float Ws[32][HD];
  int t = threadIdx.x;
  int r0 = (t >> 4) * 8;
  int c0 = (t & 15) * 8;
  long rowbase = (long)blockIdx.x * 128;

  float acc[8][8];
#pragma unroll
  for (int ci = 0; ci < 8; ci++) {
    float bv = bias[c0 + ci];
#pragma unroll
    for (int ri = 0; ri < 8; ri++) acc[ri][ci] = bv;
  }

  int sr = t >> 1;
  int hf = t & 1;
  long srow = rowbase + sr; if (srow > Nn - 1) srow = Nn - 1;
  const float* xrow = X + srow * HD;

  for (int k0 = 0; k0 < HD; k0 += 32) {
    __syncthreads();
#pragma unroll
    for (int j = 0; j < 4; j++) {
      int i = j * 1024 + t * 4;
      int kk = i >> 7, c = i & (HD - 1);
      *(float4*)&Ws[kk][c] = *(const float4*)&W[(size_t)(k0 + kk) * HD + c];
    }
#pragma unroll
    for (int j = 0; j < 4; j++) {
      int kc = k0 + hf * 16 + j * 4;
      float4 v = *(const float4*)&xrow[kc];
      int kl = hf * 16 + j * 4;
      XsT[kl + 0][sr] = v.x;
      XsT[kl + 1][sr] = v.y;
      XsT[kl + 2][sr] = v.z;
      XsT[kl + 3][sr] = v.w;
    }
    __syncthreads();
#pragma unroll 8
    for (int kk = 0; kk < 32; kk++) {
      float4 a0 = *(float4*)&XsT[kk][r0];
      float4 a1 = *(float4*)&XsT[kk][r0 + 4];
      float4 b0 = *(float4*)&Ws[kk][c0];
      float4 b1 = *(float4*)&Ws[kk][c0 + 4];
      float ar[8] = {a0.x, a0.y, a0.z, a0.w, a1.x, a1.y, a1.z, a1.w};
      float bc[8] = {b0.x, b0.y, b0.z, b0.w, b1.x, b1.y, b1.z, b1.w};
#pragma unroll
      for (int ri = 0; ri < 8; ri++)
#pragma unroll
        for (int ci = 0; ci < 8; ci++) acc[ri][ci] += ar[ri] * bc[ci];
    }
  }

#pragma unroll
  for (int ri = 0; ri < 8; ri++) {
    long row = rowbase + r0 + ri;
    if (row < Nn) {
      float4 o0 = {acc[ri][0], acc[ri][1], acc[ri][2], acc[ri][3]};
      float4 o1 = {acc[ri][4], acc[ri][5], acc[ri][6], acc[ri][7]};
      *(float4*)&out[row * HD + c0] = o0;
      *(float4*)&out[row * HD + c0 + 4] = o1;
    }
  }
}

__global__ void stats_f32(const float* __restrict__ z, float* stat, int n) {
  int c = threadIdx.x & (HD - 1);
  int rg = threadIdx.x >> 7;
  float s = 0.f, ss = 0.f;
  for (int r = blockIdx.x * 2 + rg; r < n; r += gridDim.x * 2) {
    float v = z[(size_t)r * HD + c];
    s += v; ss += v * v;
  }
  __shared__ float S[2][HD], SS[2][HD];
  S[rg][c] = s; SS[rg][c] = ss;
  __syncthreads();
  if (threadIdx.x < HD) {
    atomicAdd(&stat[c], S[0][c] + S[1][c]);
    atomicAdd(&stat[HD + c], SS[0][c] + SS[1][c]);
  }
}

__global__ void cls_out_kernel(const float* __restrict__ zc, const float* __restrict__ ab,
                               const float* __restrict__ W2, const float* __restrict__ b2,
                               float* out, int G) {
  int row = blockIdx.x;
  int t = threadIdx.x;
  float v0 = fmaxf(zc[(size_t)row * HD + t] * ab[t] + ab[HD + t], 0.f);
  float v1 = fmaxf(zc[(size_t)row * HD + 64 + t] * ab[64 + t] + ab[HD + 64 + t], 0.f);
  for (int o = 0; o < 10; o++) {
    float p = v0 * W2[t * 10 + o] + v1 * W2[(64 + t) * 10 + o];
#pragma unroll
    for (int s = 32; s > 0; s >>= 1) p += __shfl_down(p, s);
    if (t == 0) out[row * 10 + o] = p + b2[o];
  }
}

extern "C" void kernel_launch(void* const* d_in, const int* in_sizes, int n_in,
                              void* d_out, int out_size, void* d_ws, size_t ws_size,
                              hipStream_t stream) {
  const int* x     = (const int*)d_in[0];
  const int* ei    = (const int*)d_in[1];
  const int* batch = (const int*)d_in[2];
  const float* pe  = (const float*)d_in[4];
  const float* ce  = (const float*)d_in[5];
  const float* le  = (const float*)d_in[6];
  const float* cW1 = (const float*)d_in[7];
  const float* cb1 = (const float*)d_in[8];
  const float* cg1 = (const float*)d_in[9];
  const float* cbe1= (const float*)d_in[10];
  const float* cW2 = (const float*)d_in[11];
  const float* cb2 = (const float*)d_in[12];
  const float* ngm = (const float*)d_in[13];
  const float* nbe = (const float*)d_in[14];
  const float* gW1 = (const float*)d_in[15];
  const float* gb1 = (const float*)d_in[16];
  const float* gW2 = (const float*)d_in[17];
  const float* clW1= (const float*)d_in[19];
  const float* clb1= (const float*)d_in[20];
  const float* clg = (const float*)d_in[21];
  const float* clbe= (const float*)d_in[22];
  const float* clW2= (const float*)d_in[23];
  const float* clb2= (const float*)d_in[24];

  int N = in_sizes[2];
  int E = in_sizes[1] / 2;
  int G = out_size / 10;

  float* buf0   = (float*)d_ws;              // h (f32)
  float* buf1   = buf0 + (size_t)N * HD;     // h+agg / z (f32)
  float* pooled = buf1 + (size_t)N * HD;     // G x 128
  float* gate   = pooled + (size_t)G * HD;   // N
  float* zc     = gate + N;                  // G x 128
  float* stats  = zc + (size_t)G * HD;       // 7 x 1024
  float* ab     = stats + 7 * 1024;          // 7 x 256
  unsigned short* whi = (unsigned short*)(ab + 7 * 256);  // 7 x 128 x 128 bf16
  unsigned short* wlo = whi + 7 * HD * HD;
  int* csr_off  = (int*)(wlo + 7 * HD * HD); // N+1
  int* cursor   = csr_off + (N + 1);         // N
  int* bsum     = cursor + N;                // 128
  int* gs       = bsum + 128;                // G+1
  int* csr_src  = gs + (G + 1);              // E

  float* out = (float*)d_out;
  int gemmBlocks = (N + 127) / 128;
  int Wwin = (N + 7) / 8;

  zero_f<<<28, 256, 0, stream>>>(stats, 7 * 1024);
  encode_kernel<<<2048, 256, 0, stream>>>(x, pe, ce, le, buf0, N);
  prep_w<<<7, 256, 0, stream>>>(cW1, cW2, gW1, whi, wlo);

  // CSR build (reused by all 3 layers); XCD-owned dst windows
  int nb = (N + SCAN_BS - 1) / SCAN_BS;
  zero_int<<<256, 256, 0, stream>>>(cursor, N);
  hist_kernel<<<2048, 256, 0, stream>>>(ei, cursor, E, Wwin);
  scan1_kernel<<<nb, 256, 0, stream>>>(cursor, csr_off, bsum, N);
  scan2_kernel<<<1, 128, 0, stream>>>(bsum, nb);
  scan3_kernel<<<256, 256, 0, stream>>>(csr_off, cursor, bsum, N, E);
  fill_kernel<<<2048, 256, 0, stream>>>(ei, cursor, csr_src, E, Wwin);
  bound_kernel<<<(N + 255) / 256, 256, 0, stream>>>(batch, gs, N, G);

  for (int l = 0; l < 3; l++) {
    float* abPrev = ab + (l - 1) * 512 + 256;
    if (l == 0)
      gather_kernel<false><<<2048, 256, 0, stream>>>(buf0, csr_off, csr_src, nullptr, buf1, N);
    else
      gather_kernel<true><<<2048, 256, 0, stream>>>(buf0, csr_off, csr_src, abPrev, buf1, N);
    gemm_split<false, false, true><<<gemmBlocks, 512, 0, stream>>>(
        buf1, whi + (size_t)l * HD * HD, wlo + (size_t)l * HD * HD,
        cb1 + l * HD, nullptr, nullptr, buf1, nullptr, stats + l * 2048, N);
    finalize_kernel<<<1, 128, 0, stream>>>(stats + l * 2048, cg1 + l * HD, cbe1 + l * HD,
                                           ab + l * 512, 1.f / N);
    gemm_split<true, false, true><<<gemmBlocks, 512, 0, stream>>>(
        buf1, whi + (size_t)(3 + l) * HD * HD, wlo + (size_t)(3 + l) * HD * HD,
        cb2 + l * HD, ab + l * 512, nullptr, buf0, nullptr, stats + l * 2048 + 1024, N);
    finalize_kernel<<<1, 128, 0, stream>>>(stats + l * 2048 + 1024, ngm + l * HD, nbe + l * HD,
                                           ab + l * 512 + 256, 1.f / N);
  }

  const float* abFin = ab + 2 * 512 + 256;
  gemm_split<true, true, false><<<gemmBlocks, 512, 0, stream>>>(
      buf0, whi + (size_t)6 * HD * HD, wlo + (size_t)6 * HD * HD,
      gb1, abFin, gW2, nullptr, gate, nullptr, N);
  fused_pool<<<G, HD, 0, stream>>>(buf0, gate, gs, abFin, pooled);

  // classifier tail in f32
  gemm_f32<<<(G + 127) / 128, 256, 0, stream>>>(pooled, clW1, clb1, zc, G);
  stats_f32<<<64, 256, 0, stream>>>(zc, stats + 6 * 1024, G);
  finalize1_kernel<<<1, 128, 0, stream>>>(stats + 6 * 1024, clg, clbe, ab + 6 * 256, 1.f / G);
  cls_out_kernel<<<G, 64, 0, stream>>>(zc, ab + 6 * 256, clW2, clb2, out, G);
}

// Round 9
// 890.625 us; speedup vs baseline: 10.8912x; 1.0505x over previous
//
#include <hip/hip_runtime.h>
#include <math.h>

#define HD 128

typedef __attribute__((ext_vector_type(8))) short bf16x8;
typedef __attribute__((ext_vector_type(8))) unsigned short us8;
typedef __attribute__((ext_vector_type(4))) unsigned short us4;
typedef __attribute__((ext_vector_type(4))) float f32x4;

__device__ __forceinline__ float bf2f(unsigned short u) {
  union { unsigned int i; float f; } v; v.i = ((unsigned int)u) << 16; return v.f;
}
__device__ __forceinline__ unsigned short f2bf(float f) {
  union { float f; unsigned int i; } v; v.f = f;
  unsigned int u = v.i;
  u += 0x7FFFu + ((u >> 16) & 1u);
  return (unsigned short)(u >> 16);
}

__global__ void zero_f(float* p, int n) {
  int i = blockIdx.x * blockDim.x + threadIdx.x;
  if (i < n) p[i] = 0.f;
}

__global__ void zero_int(int* p, int n) {
  int stride = gridDim.x * blockDim.x;
  for (int i = blockIdx.x * blockDim.x + threadIdx.x; i < n; i += stride) p[i] = 0;
}

__global__ void encode_kernel(const int* __restrict__ x, const float* __restrict__ pe,
                              const float* __restrict__ ce, const float* __restrict__ le,
                              float* __restrict__ h, int n) {
  int total = n * HD;
  int stride = gridDim.x * blockDim.x;
  for (int idx = blockIdx.x * blockDim.x + threadIdx.x; idx < total; idx += stride) {
    int node = idx >> 7, c = idx & (HD - 1);
    int lv = x[node * 3 + 0]; lv = lv < 0 ? 0 : (lv > 999 ? 999 : lv);
    int ct = x[node * 3 + 1]; ct = ct < 0 ? 0 : (ct > 4 ? 4 : ct);
    int th = x[node * 3 + 2]; th = th < 0 ? 0 : (th > 4999 ? 4999 : th);
    h[idx] = ce[ct * HD + c] + le[lv * HD + c] + pe[th * HD + c];
  }
}

// split 7 [128][128] f32 weight mats into bf16 hi/lo in WAVE-TILED fragment layout:
// out[((ct*4+k4)*64 + lane)*8 + j] = W[k][c], c = ct*16+(lane&15), k = (k4*4+(lane>>4))*8+j
__global__ void prep_w(const float* __restrict__ cW1, const float* __restrict__ cW2,
                       const float* __restrict__ gW1,
                       unsigned short* __restrict__ whi, unsigned short* __restrict__ wlo) {
  int m = blockIdx.x;
  const float* W = (m < 3) ? cW1 + (size_t)m * HD * HD
                 : (m < 6) ? cW2 + (size_t)(m - 3) * HD * HD : gW1;
  unsigned short* oh = whi + (size_t)m * HD * HD;
  unsigned short* ol = wlo + (size_t)m * HD * HD;
  for (int i = threadIdx.x; i < HD * HD; i += 256) {
    int j = i & 7;
    int l = (i >> 3) & 63;
    int p = i >> 9;            // ct*4 + k4
    int ct = p >> 2, k4 = p & 3;
    int c = ct * 16 + (l & 15);
    int k = (k4 * 4 + (l >> 4)) * 8 + j;
    float f = W[k * HD + c];
    unsigned short hh = f2bf(f);
    oh[i] = hh;
    ol[i] = f2bf(f - bf2f(hh));
  }
}

// ---------------- CSR build (XCD-owned dst windows, see R8) ---------------------

__global__ void hist_kernel(const int* __restrict__ ei, int* deg, int E, int Wwin) {
  int pass = blockIdx.x & 7;
  int b = blockIdx.x >> 3;
  int tstride = (gridDim.x >> 3) * blockDim.x;
  for (int e = b * blockDim.x + threadIdx.x; e < E; e += tstride) {
    int d = ei[E + e];
    if (d / Wwin == pass) atomicAdd(&deg[d], 1);
  }
}

#define SCAN_BS 1024
__global__ void scan1_kernel(const int* __restrict__ deg, int* __restrict__ off,
                             int* __restrict__ bsum, int n) {
  __shared__ int sh[256];
  int b = blockIdx.x, t = threadIdx.x;
  int base = b * SCAN_BS + t * 4;
  int v[4];
#pragma unroll
  for (int j = 0; j < 4; j++) v[j] = (base + j < n) ? deg[base + j] : 0;
  int s = v[0] + v[1] + v[2] + v[3];
  sh[t] = s;
  __syncthreads();
  for (int o = 1; o < 256; o <<= 1) {
    int x = (t >= o) ? sh[t - o] : 0;
    __syncthreads();
    sh[t] += x;
    __syncthreads();
  }
  int excl = sh[t] - s;
  if (t == 255) bsum[b] = sh[255];
  int run = excl;
#pragma unroll
  for (int j = 0; j < 4; j++) {
    if (base + j < n) off[base + j] = run;
    run += v[j];
  }
}

__global__ void scan2_kernel(int* bsum, int nb) {
  __shared__ int sh[128];
  int t = threadIdx.x;
  int v = (t < nb) ? bsum[t] : 0;
  sh[t] = v;
  __syncthreads();
  for (int o = 1; o < 128; o <<= 1) {
    int x = (t >= o) ? sh[t - o] : 0;
    __syncthreads();
    sh[t] += x;
    __syncthreads();
  }
  if (t < nb) bsum[t] = sh[t] - v;
}

__global__ void scan3_kernel(int* off, int* cursor, const int* __restrict__ bsum,
                             int n, int E) {
  int idx = blockIdx.x * blockDim.x + threadIdx.x;
  int stride = gridDim.x * blockDim.x;
  for (int i = idx; i < n; i += stride) {
    int v = off[i] + bsum[i >> 10];
    off[i] = v;
    cursor[i] = v;
  }
  if (idx == 0) off[n] = E;
}

__global__ void fill_kernel(const int* __restrict__ ei, int* cursor, int* csr_src,
                            int E, int Wwin) {
  int pass = blockIdx.x & 7;
  int b = blockIdx.x >> 3;
  int tstride = (gridDim.x >> 3) * blockDim.x;
  for (int e = b * blockDim.x + threadIdx.x; e < E; e += tstride) {
    int d = ei[E + e];
    if (d / Wwin == pass) {
      int pos = atomicAdd(&cursor[d], 1);
      csr_src[pos] = ei[e];
    }
  }
}

// ---------------- fused gather + split-bf16 MFMA GEMM (GIN layer, stage 1) -----
// Per 128-row block: row_i_agg = f(h[i]) + sum_e f(h[src_e]) gathered straight
// into LDS as bf16 hi/lo (f = identity or relu(a*x+b)); then z = agg @ W^T + bias
// with A*B ~= Ah*Bh + Ah*Bl + Al*Bh; fused per-column stats.
template<bool BN, bool STATS>
__global__ __launch_bounds__(512, 4)
void gemm_gather(const float* __restrict__ h, const int* __restrict__ off,
                 const int* __restrict__ src, const float* __restrict__ ab,
                 const unsigned short* __restrict__ Whi,
                 const unsigned short* __restrict__ Wlo,
                 const float* __restrict__ bias, float* __restrict__ outf,
                 float* __restrict__ stat, int Nn) {
  __shared__ unsigned short XsH[128 * HD];
  __shared__ unsigned short XsL[128 * HD];
  __shared__ float red[2 * HD];
  int t = threadIdx.x;
  long rowbase = (long)blockIdx.x * 128;
  int grp = t >> 5, lane = t & 31;

  float4 a4, b4;
  if (BN) {
    a4 = *(const float4*)(ab + lane * 4);
    b4 = *(const float4*)(ab + HD + lane * 4);
  }
#define APPLY_BN(v) if (BN) { \
    v.x = fmaxf(v.x * a4.x + b4.x, 0.f); \
    v.y = fmaxf(v.y * a4.y + b4.y, 0.f); \
    v.z = fmaxf(v.z * a4.z + b4.z, 0.f); \
    v.w = fmaxf(v.w * a4.w + b4.w, 0.f); }

  // gather phase: 16 groups x 32 lanes; 8 rows/group; 8-deep edge unroll
  for (int rr = 0; rr < 8; rr++) {
    int r = grp + rr * 16;
    long row = rowbase + r; if (row > Nn - 1) row = Nn - 1;
    int s0 = off[row], s1 = off[row + 1];
    float4 acc0 = *(const float4*)(h + row * HD + lane * 4);
    APPLY_BN(acc0);
    float4 acc1 = {0.f, 0.f, 0.f, 0.f};
    float4 acc2 = {0.f, 0.f, 0.f, 0.f};
    float4 acc3 = {0.f, 0.f, 0.f, 0.f};
    int e = s0;
    for (; e + 8 <= s1; e += 8) {
      int i0 = src[e], i1 = src[e + 1], i2 = src[e + 2], i3 = src[e + 3];
      int i4 = src[e + 4], i5 = src[e + 5], i6 = src[e + 6], i7 = src[e + 7];
      float4 v0 = *(const float4*)(h + (size_t)i0 * HD + lane * 4);
      float4 v1 = *(const float4*)(h + (size_t)i1 * HD + lane * 4);
      float4 v2 = *(const float4*)(h + (size_t)i2 * HD + lane * 4);
      float4 v3 = *(const float4*)(h + (size_t)i3 * HD + lane * 4);
      float4 v4 = *(const float4*)(h + (size_t)i4 * HD + lane * 4);
      float4 v5 = *(const float4*)(h + (size_t)i5 * HD + lane * 4);
      float4 v6 = *(const float4*)(h + (size_t)i6 * HD + lane * 4);
      float4 v7 = *(const float4*)(h + (size_t)i7 * HD + lane * 4);
      APPLY_BN(v0); APPLY_BN(v1); APPLY_BN(v2); APPLY_BN(v3);
      APPLY_BN(v4); APPLY_BN(v5); APPLY_BN(v6); APPLY_BN(v7);
      acc0.x += v0.x + v4.x; acc0.y += v0.y + v4.y; acc0.z += v0.z + v4.z; acc0.w += v0.w + v4.w;
      acc1.x += v1.x + v5.x; acc1.y += v1.y + v5.y; acc1.z += v1.z + v5.z; acc1.w += v1.w + v5.w;
      acc2.x += v2.x + v6.x; acc2.y += v2.y + v6.y; acc2.z += v2.z + v6.z; acc2.w += v2.w + v6.w;
      acc3.x += v3.x + v7.x; acc3.y += v3.y + v7.y; acc3.z += v3.z + v7.z; acc3.w += v3.w + v7.w;
    }
    for (; e < s1; e++) {
      int s = src[e];
      float4 v = *(const float4*)(h + (size_t)s * HD + lane * 4);
      APPLY_BN(v);
      acc0.x += v.x; acc0.y += v.y; acc0.z += v.z; acc0.w += v.w;
    }
    acc0.x += acc1.x + acc2.x + acc3.x;
    acc0.y += acc1.y + acc2.y + acc3.y;
    acc0.z += acc1.z + acc2.z + acc3.z;
    acc0.w += acc1.w + acc2.w + acc3.w;
    // split to bf16 hi/lo, swizzled store (granule = 8 elems; lane covers 4)
    float f[4] = {acc0.x, acc0.y, acc0.z, acc0.w};
    us4 hi, lo;
#pragma unroll
    for (int j = 0; j < 4; j++) {
      unsigned short hh = f2bf(f[j]);
      hi[j] = hh;
      lo[j] = f2bf(f[j] - bf2f(hh));
    }
    int g8 = lane >> 1;
    int offl = r * HD + (((g8 ^ (r & 7)) << 3)) + (lane & 1) * 4;
    *(us4*)(XsH + offl) = hi;
    *(us4*)(XsL + offl) = lo;
  }
#undef APPLY_BN
  if (STATS && t < 2 * HD) red[t] = 0.f;
  __syncthreads();

  int w = t >> 6, l = t & 63;
  int lr = l & 15, lg = l >> 4;

  f32x4 acc[8];
#pragma unroll
  for (int ct = 0; ct < 8; ct++) acc[ct] = (f32x4){0.f, 0.f, 0.f, 0.f};

  bf16x8 aH[4], aL[4];
  int arow = w * 16 + lr;
#pragma unroll
  for (int k4 = 0; k4 < 4; k4++) {
    int kg = k4 * 4 + lg;
    int offa = arow * HD + (((kg ^ (arow & 7)) << 3));
    aH[k4] = *(bf16x8*)(XsH + offa);
    aL[k4] = *(bf16x8*)(XsL + offa);
  }
#pragma unroll
  for (int ct = 0; ct < 8; ct++) {
#pragma unroll
    for (int k4 = 0; k4 < 4; k4++) {
      int bo = (((ct << 2) + k4) * 64 + l) * 8;
      bf16x8 bH = *(const bf16x8*)(Whi + bo);
      bf16x8 bL = *(const bf16x8*)(Wlo + bo);
      acc[ct] = __builtin_amdgcn_mfma_f32_16x16x32_bf16(aH[k4], bH, acc[ct], 0, 0, 0);
      acc[ct] = __builtin_amdgcn_mfma_f32_16x16x32_bf16(aH[k4], bL, acc[ct], 0, 0, 0);
      acc[ct] = __builtin_amdgcn_mfma_f32_16x16x32_bf16(aL[k4], bH, acc[ct], 0, 0, 0);
    }
  }

  float s[8], ss[8];
#pragma unroll
  for (int ct = 0; ct < 8; ct++) { s[ct] = 0.f; ss[ct] = 0.f; }
#pragma unroll
  for (int jj = 0; jj < 4; jj++) {
    long row = rowbase + w * 16 + lg * 4 + jj;
    bool ok = row < Nn;
#pragma unroll
    for (int ct = 0; ct < 8; ct++) {
      float v = acc[ct][jj] + bias[ct * 16 + lr];
      if (ok) {
        outf[row * HD + ct * 16 + lr] = v;
        if (STATS) { s[ct] += v; ss[ct] += v * v; }
      }
    }
  }
  if (STATS) {
#pragma unroll
    for (int ct = 0; ct < 8; ct++) {
      float sv = s[ct], sq = ss[ct];
      sv += __shfl_xor(sv, 16); sq += __shfl_xor(sq, 16);
      sv += __shfl_xor(sv, 32); sq += __shfl_xor(sq, 32);
      if (lg == 0) {
        atomicAdd(&red[ct * 16 + lr], sv);
        atomicAdd(&red[HD + ct * 16 + lr], sq);
      }
    }
    __syncthreads();
    float* st = stat + (blockIdx.x & 3) * 256;
    if (t < HD) {
      atomicAdd(&st[t], red[t]);
      atomicAdd(&st[HD + t], red[HD + t]);
    }
  }
}

// ---------------- split-bf16 MFMA GEMM (contiguous input) ----------------------
template<bool INBN, bool GATE, bool STATS>
__global__ __launch_bounds__(512, 4)
void gemm_split(const float* __restrict__ X, const unsigned short* __restrict__ Whi,
                const unsigned short* __restrict__ Wlo,
                const float* __restrict__ bias, const float* __restrict__ ab,
                const float* __restrict__ w2, float* __restrict__ outf,
                float* __restrict__ gate, float* __restrict__ stat, int Nn) {
  __shared__ unsigned short XsH[128 * HD];
  __shared__ unsigned short XsL[128 * HD];
  __shared__ float red[2 * HD];
  int t = threadIdx.x;
  long rowbase = (long)blockIdx.x * 128;

#pragma unroll
  for (int it = 0; it < 8; it++) {
    int i = (t + it * 512) * 4;
    int r = i >> 7, k = i & (HD - 1);
    long row = rowbase + r; if (row > Nn - 1) row = Nn - 1;
    float4 v = *(const float4*)(X + row * HD + k);
    float f[4] = {v.x, v.y, v.z, v.w};
    if (INBN) {
#pragma unroll
      for (int j = 0; j < 4; j++)
        f[j] = fmaxf(f[j] * ab[k + j] + ab[HD + k + j], 0.f);
    }
    us4 hi, lo;
#pragma unroll
    for (int j = 0; j < 4; j++) {
      unsigned short hh = f2bf(f[j]);
      hi[j] = hh;
      lo[j] = f2bf(f[j] - bf2f(hh));
    }
    int g = k >> 3;
    int off = r * HD + ((((g ^ (r & 7)) << 3)) | (k & 7));
    *(us4*)(XsH + off) = hi;
    *(us4*)(XsL + off) = lo;
  }
  if (STATS && t < 2 * HD) red[t] = 0.f;
  __syncthreads();

  int w = t >> 6, l = t & 63;
  int lr = l & 15, lg = l >> 4;

  f32x4 acc[8];
#pragma unroll
  for (int ct = 0; ct < 8; ct++) acc[ct] = (f32x4){0.f, 0.f, 0.f, 0.f};

  bf16x8 aH[4], aL[4];
  int arow = w * 16 + lr;
#pragma unroll
  for (int k4 = 0; k4 < 4; k4++) {
    int kg = k4 * 4 + lg;
    int off = arow * HD + (((kg ^ (arow & 7)) << 3));
    aH[k4] = *(bf16x8*)(XsH + off);
    aL[k4] = *(bf16x8*)(XsL + off);
  }
#pragma unroll
  for (int ct = 0; ct < 8; ct++) {
#pragma unroll
    for (int k4 = 0; k4 < 4; k4++) {
      int bo = (((ct << 2) + k4) * 64 + l) * 8;
      bf16x8 bH = *(const bf16x8*)(Whi + bo);
      bf16x8 bL = *(const bf16x8*)(Wlo + bo);
      acc[ct] = __builtin_amdgcn_mfma_f32_16x16x32_bf16(aH[k4], bH, acc[ct], 0, 0, 0);
      acc[ct] = __builtin_amdgcn_mfma_f32_16x16x32_bf16(aH[k4], bL, acc[ct], 0, 0, 0);
      acc[ct] = __builtin_amdgcn_mfma_f32_16x16x32_bf16(aL[k4], bH, acc[ct], 0, 0, 0);
    }
  }

  if (GATE) {
#pragma unroll
    for (int jj = 0; jj < 4; jj++) {
      float p = 0.f;
#pragma unroll
      for (int ct = 0; ct < 8; ct++) {
        float v = fmaxf(acc[ct][jj] + bias[ct * 16 + lr], 0.f);
        p += v * w2[ct * 16 + lr];
      }
      p += __shfl_xor(p, 1);
      p += __shfl_xor(p, 2);
      p += __shfl_xor(p, 4);
      p += __shfl_xor(p, 8);
      long row = rowbase + w * 16 + lg * 4 + jj;
      if (lr == 0 && row < Nn) gate[row] = p;
    }
  } else {
    float s[8], ss[8];
#pragma unroll
    for (int ct = 0; ct < 8; ct++) { s[ct] = 0.f; ss[ct] = 0.f; }
#pragma unroll
    for (int jj = 0; jj < 4; jj++) {
      long row = rowbase + w * 16 + lg * 4 + jj;
      bool ok = row < Nn;
#pragma unroll
      for (int ct = 0; ct < 8; ct++) {
        float v = acc[ct][jj] + bias[ct * 16 + lr];
        if (ok) {
          outf[row * HD + ct * 16 + lr] = v;
          if (STATS) { s[ct] += v; ss[ct] += v * v; }
        }
      }
    }
    if (STATS) {
#pragma unroll
      for (int ct = 0; ct < 8; ct++) {
        float sv = s[ct], sq = ss[ct];
        sv += __shfl_xor(sv, 16); sq += __shfl_xor(sq, 16);
        sv += __shfl_xor(sv, 32); sq += __shfl_xor(sq, 32);
        if (lg == 0) {
          atomicAdd(&red[ct * 16 + lr], sv);
          atomicAdd(&red[HD + ct * 16 + lr], sq);
        }
      }
      __syncthreads();
      float* st = stat + (blockIdx.x & 3) * 256;
      if (t < HD) {
        atomicAdd(&st[t], red[t]);
        atomicAdd(&st[HD + t], red[HD + t]);
      }
    }
  }
}

__global__ void finalize_kernel(const float* __restrict__ stat, const float* __restrict__ g,
                                const float* __restrict__ be, float* ab, float inv_n) {
  int c = threadIdx.x;
  float s = stat[c] + stat[256 + c] + stat[512 + c] + stat[768 + c];
  float sq = stat[HD + c] + stat[256 + HD + c] + stat[512 + HD + c] + stat[768 + HD + c];
  float mean = s * inv_n;
  float var = sq * inv_n - mean * mean;
  float inv = rsqrtf(var + 1e-5f);
  float a = inv * g[c];
  ab[c] = a;
  ab[HD + c] = be[c] - mean * a;
}

__global__ void finalize1_kernel(const float* __restrict__ stat, const float* __restrict__ g,
                                 const float* __restrict__ be, float* ab, float inv_n) {
  int c = threadIdx.x;
  float mean = stat[c] * inv_n;
  float var = stat[HD + c] * inv_n - mean * mean;
  float inv = rsqrtf(var + 1e-5f);
  float a = inv * g[c];
  ab[c] = a;
  ab[HD + c] = be[c] - mean * a;
}

__global__ void bound_kernel(const int* __restrict__ batch, int* gs, int N, int G) {
  int i = blockIdx.x * blockDim.x + threadIdx.x;
  if (i >= N) return;
  int b = batch[i];
  int prev = (i == 0) ? -1 : batch[i - 1];
  for (int g = prev + 1; g <= b; g++) gs[g] = i;
  if (i == N - 1)
    for (int g = b + 1; g <= G; g++) gs[g] = N;
}

__global__ void fused_pool(const float* __restrict__ h, const float* __restrict__ gate,
                           const int* __restrict__ gs, const float* __restrict__ ab,
                           float* __restrict__ pooled) {
  int g = blockIdx.x;
  int t = threadIdx.x;
  int s0 = gs[g], s1 = gs[g + 1];
  if (s0 >= s1) { pooled[(size_t)g * HD + t] = 0.f; return; }
  __shared__ float red[HD];
  float m = -INFINITY;
  for (int i = s0 + t; i < s1; i += HD) m = fmaxf(m, gate[i]);
  red[t] = m;
  __syncthreads();
  for (int o = 64; o > 0; o >>= 1) {
    if (t < o) red[t] = fmaxf(red[t], red[t + o]);
    __syncthreads();
  }
  m = red[0];
  __syncthreads();
  float s = 0.f;
  for (int i = s0 + t; i < s1; i += HD) s += expf(gate[i] - m);
  red[t] = s;
  __syncthreads();
  for (int o = 64; o > 0; o >>= 1) {
    if (t < o) red[t] += red[t + o];
    __syncthreads();
  }
  float inv = 1.f / red[0];
  float a = ab[t], b = ab[HD + t];
  float acc = 0.f;
  int i = s0;
  for (; i + 4 <= s1; i += 4) {
    float al0 = expf(gate[i] - m);
    float al1 = expf(gate[i + 1] - m);
    float al2 = expf(gate[i + 2] - m);
    float al3 = expf(gate[i + 3] - m);
    float v0 = fmaxf(h[(size_t)(i + 0) * HD + t] * a + b, 0.f);
    float v1 = fmaxf(h[(size_t)(i + 1) * HD + t] * a + b, 0.f);
    float v2 = fmaxf(h[(size_t)(i + 2) * HD + t] * a + b, 0.f);
    float v3 = fmaxf(h[(size_t)(i + 3) * HD + t] * a + b, 0.f);
    acc += al0 * v0 + al1 * v1 + al2 * v2 + al3 * v3;
  }
  for (; i < s1; i++) {
    float al = expf(gate[i] - m);
    float v = fmaxf(h[(size_t)i * HD + t] * a + b, 0.f);
    acc += al * v;
  }
  pooled[(size_t)g * HD + t] = acc * inv;
}

// f32 classifier GEMM: zc[G x 128] = pooled @ W + bias
__global__ __launch_bounds__(256, 4)
void gemm_f32(const float* __restrict__ X, const float* __restrict__ W,
              const float* __restrict__ bias, float* __restrict__ out, int Nn) {
  __shared__ float XsT[32][132];
  __shared__ float Ws[32][HD];
  int t = threadIdx.x;
  int r0 = (t >> 4) * 8;
  int c0 = (t & 15) * 8;
  long rowbase = (long)blockIdx.x * 128;

  float acc[8][8];
#pragma unroll
  for (int ci = 0; ci < 8; ci++) {
    float bv = bias[c0 + ci];
#pragma unroll
    for (int ri = 0; ri < 8; ri++) acc[ri][ci] = bv;
  }

  int sr = t >> 1;
  int hf = t & 1;
  long srow = rowbase + sr; if (srow > Nn - 1) srow = Nn - 1;
  const float* xrow = X + srow * HD;

  for (int k0 = 0; k0 < HD; k0 += 32) {
    __syncthreads();
#pragma unroll
    for (int j = 0; j < 4; j++) {
      int i = j * 1024 + t * 4;
      int kk = i >> 7, c = i & (HD - 1);
      *(float4*)&Ws[kk][c] = *(const float4*)&W[(size_t)(k0 + kk) * HD + c];
    }
#pragma unroll
    for (int j = 0; j < 4; j++) {
      int kc = k0 + hf * 16 + j * 4;
      float4 v = *(const float4*)&xrow[kc];
      int kl = hf * 16 + j * 4;
      XsT[kl + 0][sr] = v.x;
      XsT[kl + 1][sr] = v.y;
      XsT[kl + 2][sr] = v.z;
      XsT[kl + 3][sr] = v.w;
    }
    __syncthreads();
#pragma unroll 8
    for (int kk = 0; kk < 32; kk++) {
      float4 a0 = *(float4*)&XsT[kk][r0];
      float4 a1 = *(float4*)&XsT[kk][r0 + 4];
      float4 b0 = *(float4*)&Ws[kk][c0];
      float4 b1 = *(float4*)&Ws[kk][c0 + 4];
      float ar[8] = {a0.x, a0.y, a0.z, a0.w, a1.x, a1.y, a1.z, a1.w};
      float bc[8] = {b0.x, b0.y, b0.z, b0.w, b1.x, b1.y, b1.z, b1.w};
#pragma unroll
      for (int ri = 0; ri < 8; ri++)
#pragma unroll
        for (int ci = 0; ci < 8; ci++) acc[ri][ci] += ar[ri] * bc[ci];
    }
  }

#pragma unroll
  for (int ri = 0; ri < 8; ri++) {
    long row = rowbase + r0 + ri;
    if (row < Nn) {
      float4 o0 = {acc[ri][0], acc[ri][1], acc[ri][2], acc[ri][3]};
      float4 o1 = {acc[ri][4], acc[ri][5], acc[ri][6], acc[ri][7]};
      *(float4*)&out[row * HD + c0] = o0;
      *(float4*)&out[row * HD + c0 + 4] = o1;
    }
  }
}

__global__ void stats_f32(const float* __restrict__ z, float* stat, int n) {
  int c = threadIdx.x & (HD - 1);
  int rg = threadIdx.x >> 7;
  float s = 0.f, ss = 0.f;
  for (int r = blockIdx.x * 2 + rg; r < n; r += gridDim.x * 2) {
    float v = z[(size_t)r * HD + c];
    s += v; ss += v * v;
  }
  __shared__ float S[2][HD], SS[2][HD];
  S[rg][c] = s; SS[rg][c] = ss;
  __syncthreads();
  if (threadIdx.x < HD) {
    atomicAdd(&stat[c], S[0][c] + S[1][c]);
    atomicAdd(&stat[HD + c], SS[0][c] + SS[1][c]);
  }
}

__global__ void cls_out_kernel(const float* __restrict__ zc, const float* __restrict__ ab,
                               const float* __restrict__ W2, const float* __restrict__ b2,
                               float* out, int G) {
  int row = blockIdx.x;
  int t = threadIdx.x;
  float v0 = fmaxf(zc[(size_t)row * HD + t] * ab[t] + ab[HD + t], 0.f);
  float v1 = fmaxf(zc[(size_t)row * HD + 64 + t] * ab[64 + t] + ab[HD + 64 + t], 0.f);
  for (int o = 0; o < 10; o++) {
    float p = v0 * W2[t * 10 + o] + v1 * W2[(64 + t) * 10 + o];
#pragma unroll
    for (int s = 32; s > 0; s >>= 1) p += __shfl_down(p, s);
    if (t == 0) out[row * 10 + o] = p + b2[o];
  }
}

extern "C" void kernel_launch(void* const* d_in, const int* in_sizes, int n_in,
                              void* d_out, int out_size, void* d_ws, size_t ws_size,
                              hipStream_t stream) {
  const int* x     = (const int*)d_in[0];
  const int* ei    = (const int*)d_in[1];
  const int* batch = (const int*)d_in[2];
  const float* pe  = (const float*)d_in[4];
  const float* ce  = (const float*)d_in[5];
  const float* le  = (const float*)d_in[6];
  const float* cW1 = (const float*)d_in[7];
  const float* cb1 = (const float*)d_in[8];
  const float* cg1 = (const float*)d_in[9];
  const float* cbe1= (const float*)d_in[10];
  const float* cW2 = (const float*)d_in[11];
  const float* cb2 = (const float*)d_in[12];
  const float* ngm = (const float*)d_in[13];
  const float* nbe = (const float*)d_in[14];
  const float* gW1 = (const float*)d_in[15];
  const float* gb1 = (const float*)d_in[16];
  const float* gW2 = (const float*)d_in[17];
  const float* clW1= (const float*)d_in[19];
  const float* clb1= (const float*)d_in[20];
  const float* clg = (const float*)d_in[21];
  const float* clbe= (const float*)d_in[22];
  const float* clW2= (const float*)d_in[23];
  const float* clb2= (const float*)d_in[24];

  int N = in_sizes[2];
  int E = in_sizes[1] / 2;
  int G = out_size / 10;

  float* buf0   = (float*)d_ws;              // h (f32)
  float* buf1   = buf0 + (size_t)N * HD;     // z (f32)
  float* pooled = buf1 + (size_t)N * HD;     // G x 128
  float* gate   = pooled + (size_t)G * HD;   // N
  float* zc     = gate + N;                  // G x 128
  float* stats  = zc + (size_t)G * HD;       // 7 x 1024
  float* ab     = stats + 7 * 1024;          // 7 x 256
  unsigned short* whi = (unsigned short*)(ab + 7 * 256);  // 7 x 128 x 128 bf16
  unsigned short* wlo = whi + 7 * HD * HD;
  int* csr_off  = (int*)(wlo + 7 * HD * HD); // N+1
  int* cursor   = csr_off + (N + 1);         // N
  int* bsum     = cursor + N;                // 128
  int* gs       = bsum + 128;                // G+1
  int* csr_src  = gs + (G + 1);              // E

  float* out = (float*)d_out;
  int gemmBlocks = (N + 127) / 128;
  int Wwin = (N + 7) / 8;

  zero_f<<<28, 256, 0, stream>>>(stats, 7 * 1024);
  encode_kernel<<<2048, 256, 0, stream>>>(x, pe, ce, le, buf0, N);
  prep_w<<<7, 256, 0, stream>>>(cW1, cW2, gW1, whi, wlo);

  // CSR build (XCD-owned dst windows; reused by all 3 layers)
  int nb = (N + SCAN_BS - 1) / SCAN_BS;
  zero_int<<<256, 256, 0, stream>>>(cursor, N);
  hist_kernel<<<2048, 256, 0, stream>>>(ei, cursor, E, Wwin);
  scan1_kernel<<<nb, 256, 0, stream>>>(cursor, csr_off, bsum, N);
  scan2_kernel<<<1, 128, 0, stream>>>(bsum, nb);
  scan3_kernel<<<256, 256, 0, stream>>>(csr_off, cursor, bsum, N, E);
  fill_kernel<<<2048, 256, 0, stream>>>(ei, cursor, csr_src, E, Wwin);
  bound_kernel<<<(N + 255) / 256, 256, 0, stream>>>(batch, gs, N, G);

  for (int l = 0; l < 3; l++) {
    float* abPrev = ab + (l - 1) * 512 + 256;
    // z = (f(h) + sum f(h_src)) @ W1 + b1  (fused gather+GEMM; f=BN+ReLU for l>0)
    if (l == 0)
      gemm_gather<false, true><<<gemmBlocks, 512, 0, stream>>>(
          buf0, csr_off, csr_src, nullptr,
          whi + (size_t)l * HD * HD, wlo + (size_t)l * HD * HD,
          cb1 + l * HD, buf1, stats + l * 2048, N);
    else
      gemm_gather<true, true><<<gemmBlocks, 512, 0, stream>>>(
          buf0, csr_off, csr_src, abPrev,
          whi + (size_t)l * HD * HD, wlo + (size_t)l * HD * HD,
          cb1 + l * HD, buf1, stats + l * 2048, N);
    finalize_kernel<<<1, 128, 0, stream>>>(stats + l * 2048, cg1 + l * HD, cbe1 + l * HD,
                                           ab + l * 512, 1.f / N);
    gemm_split<true, false, true><<<gemmBlocks, 512, 0, stream>>>(
        buf1, whi + (size_t)(3 + l) * HD * HD, wlo + (size_t)(3 + l) * HD * HD,
        cb2 + l * HD, ab + l * 512, nullptr, buf0, nullptr, stats + l * 2048 + 1024, N);
    finalize_kernel<<<1, 128, 0, stream>>>(stats + l * 2048 + 1024, ngm + l * HD, nbe + l * HD,
                                           ab + l * 512 + 256, 1.f / N);
  }

  const float* abFin = ab + 2 * 512 + 256;
  gemm_split<true, true, false><<<gemmBlocks, 512, 0, stream>>>(
      buf0, whi + (size_t)6 * HD * HD, wlo + (size_t)6 * HD * HD,
      gb1, abFin, gW2, nullptr, gate, nullptr, N);
  fused_pool<<<G, HD, 0, stream>>>(buf0, gate, gs, abFin, pooled);

  // classifier tail in f32
  gemm_f32<<<(G + 127) / 128, 256, 0, stream>>>(pooled, clW1, clb1, zc, G);
  stats_f32<<<64, 256, 0, stream>>>(zc, stats + 6 * 1024, G);
  finalize1_kernel<<<1, 128, 0, stream>>>(stats + 6 * 1024, clg, clbe, ab + 6 * 256, 1.f / G);
  cls_out_kernel<<<G, 64, 0, stream>>>(zc, ab + 6 * 256, clW2, clb2, out, G);
}